// Round 1
// baseline (1011.234 us; speedup 1.0000x reference)
//
#include <hip/hip_runtime.h>
#include <math.h>

#define B_ 4
#define N_ 4096
#define C_ 64
#define K1_ 4
#define K2_ 6
#define EPS_ 1e-5f

#define MODE_GATHER 0
#define MODE_PLAIN 2

// ---------------- pose: pos1_w = qrot(q_coarse, pos1) + t_coarse ----------------
__global__ __launch_bounds__(256) void k_pose(const float* __restrict__ pos1,
                                              const float* __restrict__ qc,
                                              const float* __restrict__ tc,
                                              float* __restrict__ posw) {
  int t = blockIdx.x * 256 + threadIdx.x;
  if (t >= B_ * N_) return;
  int b = t / N_;
  float qw = qc[b * 4 + 0], qx = qc[b * 4 + 1], qy = qc[b * 4 + 2], qz = qc[b * 4 + 3];
  float vx = pos1[t * 3 + 0], vy = pos1[t * 3 + 1], vz = pos1[t * 3 + 2];
  // quat_mul(q, [0,v])
  float aw = -(qx * vx + qy * vy + qz * vz);
  float ax = qw * vx + qy * vz - qz * vy;
  float ay = qw * vy - qx * vz + qz * vx;
  float az = qw * vz + qx * vy - qy * vx;
  // inv_q(q)
  float n2 = qw * qw + qx * qx + qy * qy + qz * qz + 1e-10f;
  float bw = qw / n2, bx = -qx / n2, by = -qy / n2, bz = -qz / n2;
  // quat_mul(A, invq), xyz part
  float rx = aw * bx + ax * bw + ay * bz - az * by;
  float ry = aw * by - ax * bz + ay * bw + az * bx;
  float rz = aw * bz + ax * by - ay * bx + az * bw;
  posw[t * 3 + 0] = rx + tc[b * 3 + 0];
  posw[t * 3 + 1] = ry + tc[b * 3 + 1];
  posw[t * 3 + 2] = rz + tc[b * 3 + 2];
}

// ---------------- chunked KNN (stable top-k, jax tie-break = lower index) ------
template <int K>
__global__ __launch_bounds__(256) void k_knn_part(const float* __restrict__ qpos,
                                                  const float* __restrict__ ppos,
                                                  float* __restrict__ outD,
                                                  int* __restrict__ outI) {
  __shared__ float4 pts[1024];
  int b = blockIdx.z;
  int cy = blockIdx.y;
  int base = cy * 1024;
  for (int i = threadIdx.x; i < 1024; i += 256) {
    const float* p = ppos + (size_t)(b * N_ + base + i) * 3;
    float x = p[0], y = p[1], z = p[2];
    pts[i] = make_float4(x, y, z, x * x + y * y + z * z);
  }
  __syncthreads();
  int n = blockIdx.x * 256 + threadIdx.x;
  const float* q = qpos + (size_t)(b * N_ + n) * 3;
  float qx = q[0], qy = q[1], qz = q[2];
  float qq = qx * qx + qy * qy + qz * qz;
  float bd[K];
  int bi[K];
#pragma unroll
  for (int t = 0; t < K; ++t) { bd[t] = INFINITY; bi[t] = 0x7fffffff; }
  for (int j = 0; j < 1024; ++j) {
    float4 p = pts[j];
    float d = qq + p.w - 2.f * (qx * p.x + qy * p.y + qz * p.z);
    if (d < bd[K - 1]) {
      int pos = 0;
#pragma unroll
      for (int t = 0; t < K - 1; ++t) pos += (bd[t] <= d) ? 1 : 0;  // insert AFTER equals (stable)
#pragma unroll
      for (int u = K - 1; u > 0; --u) {
        bool mv = (u > pos);
        bd[u] = mv ? bd[u - 1] : bd[u];
        bi[u] = mv ? bi[u - 1] : bi[u];
      }
#pragma unroll
      for (int u = 0; u < K; ++u) {
        if (u == pos) { bd[u] = d; bi[u] = base + j; }
      }
    }
  }
  size_t ob = ((size_t)(b * N_ + n) * 4 + cy) * K;
#pragma unroll
  for (int t = 0; t < K; ++t) { outD[ob + t] = bd[t]; outI[ob + t] = bi[t]; }
}

template <int K>
__global__ __launch_bounds__(256) void k_knn_merge(const float* __restrict__ inD,
                                                   const int* __restrict__ inI,
                                                   int* __restrict__ idx) {
  int t = blockIdx.x * 256 + threadIdx.x;
  if (t >= B_ * N_) return;
  float bd[K];
  int bi[K];
#pragma unroll
  for (int u = 0; u < K; ++u) { bd[u] = INFINITY; bi[u] = 0x7fffffff; }
  size_t ib = (size_t)t * 4 * K;
  for (int c = 0; c < 4 * K; ++c) {  // chunks in ascending index order -> stable
    float d = inD[ib + c];
    int j = inI[ib + c];
    if (d < bd[K - 1]) {
      int pos = 0;
#pragma unroll
      for (int u = 0; u < K - 1; ++u) pos += (bd[u] <= d) ? 1 : 0;
#pragma unroll
      for (int u = K - 1; u > 0; --u) {
        bool mv = (u > pos);
        bd[u] = mv ? bd[u - 1] : bd[u];
        bi[u] = mv ? bi[u - 1] : bi[u];
      }
#pragma unroll
      for (int u = 0; u < K; ++u) {
        if (u == pos) { bd[u] = d; bi[u] = j; }
      }
    }
  }
#pragma unroll
  for (int u = 0; u < K; ++u) idx[(size_t)t * K + u] = bi[u];
}

// ---------------- fused gather/BN-relu + GEMM layer ----------------------------
// y[row][o] = sum_c x[row][c] * W[o][c]; accumulates per-channel sum/sumsq stats.
template <int CIN, int COUT, int MODE, int KNN>
__global__ __launch_bounds__(256) void k_layer(
    const float* __restrict__ W, const float* __restrict__ posP,
    const float* __restrict__ posQ, const float* __restrict__ featN,
    const float* __restrict__ feat1, const int* __restrict__ idx,
    const float* __restrict__ yprev, const float* __restrict__ statPrev,
    const float* __restrict__ gPrev, const float* __restrict__ bPrev,
    float prevInvM, float* __restrict__ yout, float* __restrict__ statOut) {
  constexpr int CHUNK = 32;
  constexpr int NCH = (CIN + CHUNK - 1) / CHUNK;
  constexpr int CINP = NCH * CHUNK;
  constexpr int XST = 68;  // 64 rows + 4 pad (bank spread, keeps 16B alignment)
  __shared__ float Xs[CINP * XST];
  __shared__ float Wc[CHUNK * COUT];
  __shared__ float scl[CIN];
  __shared__ float shf[CIN];

  int tid = threadIdx.x;
  int row0 = blockIdx.x * 64;

  if (MODE == MODE_PLAIN) {
    for (int c = tid; c < CIN; c += 256) {
      float s = 0.f, s2 = 0.f;
#pragma unroll
      for (int u = 0; u < 8; ++u) {
        s += statPrev[c * 8 + u];
        s2 += statPrev[CIN * 8 + c * 8 + u];
      }
      float m = s * prevInvM;
      float v = s2 * prevInvM - m * m;
      float sc = gPrev[c] * rsqrtf(v + EPS_);
      scl[c] = sc;
      shf[c] = bPrev[c] - m * sc;
    }
    __syncthreads();
  }

  // Build X tile transposed: Xs[c][r]
  for (int e = tid; e < CINP * 64; e += 256) {
    int r = e / CINP;
    int c = e - r * CINP;
    float x = 0.f;
    if (c < CIN) {
      int row = row0 + r;
      if (MODE == MODE_PLAIN) {
        float y = yprev[(size_t)row * CIN + c];
        x = fmaxf(fmaf(y, scl[c], shf[c]), 0.f);
      } else {
        int b = row / (N_ * KNN);
        int rem = row - b * (N_ * KNN);
        int n = rem / KNN;
        int j = idx[row];
        if (c < 3)
          x = posP[(size_t)(b * N_ + j) * 3 + c] - posQ[(size_t)(b * N_ + n) * 3 + c];
        else if (c < 3 + C_)
          x = featN[(size_t)(b * N_ + j) * C_ + (c - 3)];
        else
          x = feat1[(size_t)(b * N_ + n) * C_ + (c - 3 - C_)];
      }
    }
    Xs[c * XST + r] = x;
  }

  constexpr int CG = COUT / 4;
  constexpr int RG = 256 / CG;
  constexpr int TR = 64 / RG;
  int cg = tid % CG;
  int rg = tid / CG;

  float acc[TR][4];
#pragma unroll
  for (int r = 0; r < TR; ++r)
#pragma unroll
    for (int q = 0; q < 4; ++q) acc[r][q] = 0.f;

  for (int ch = 0; ch < NCH; ++ch) {
    int c0 = ch * CHUNK;
    __syncthreads();  // Xs ready (ch=0) / prev chunk compute done
    for (int e = tid; e < CHUNK * COUT; e += 256) {
      int cl = e / COUT;
      int o = e - cl * COUT;
      int c = c0 + cl;
      Wc[e] = (c < CIN) ? W[(size_t)o * CIN + c] : 0.f;  // Wc[cl][o]
    }
    __syncthreads();
#pragma unroll
    for (int cl = 0; cl < CHUNK; ++cl) {
      const float4 w4 = *(const float4*)&Wc[cl * COUT + cg * 4];
      const float* xp = &Xs[(c0 + cl) * XST + rg * TR];
#pragma unroll
      for (int rr = 0; rr < TR / 4; ++rr) {
        float4 x4 = *(const float4*)(xp + rr * 4);
        float xv[4] = {x4.x, x4.y, x4.z, x4.w};
#pragma unroll
        for (int r = 0; r < 4; ++r) {
          int rt = rr * 4 + r;
          acc[rt][0] = fmaf(xv[r], w4.x, acc[rt][0]);
          acc[rt][1] = fmaf(xv[r], w4.y, acc[rt][1]);
          acc[rt][2] = fmaf(xv[r], w4.z, acc[rt][2]);
          acc[rt][3] = fmaf(xv[r], w4.w, acc[rt][3]);
        }
      }
    }
  }

  // write output + per-thread stat partials
  float s1[4] = {0, 0, 0, 0}, s2[4] = {0, 0, 0, 0};
#pragma unroll
  for (int r = 0; r < TR; ++r) {
    int row = row0 + rg * TR + r;
    float4 v = make_float4(acc[r][0], acc[r][1], acc[r][2], acc[r][3]);
    *(float4*)&yout[(size_t)row * COUT + cg * 4] = v;
#pragma unroll
    for (int q = 0; q < 4; ++q) {
      s1[q] += acc[r][q];
      s2[q] += acc[r][q] * acc[r][q];
    }
  }

  __syncthreads();  // done reading Xs -> reuse as reduction scratch
  float* red = Xs;
  int slot = blockIdx.x & 7;
#pragma unroll
  for (int q = 0; q < 4; ++q) red[rg * COUT + cg * 4 + q] = s1[q];
  __syncthreads();
  if (tid < COUT) {
    float tsum = 0.f;
#pragma unroll
    for (int r = 0; r < RG; ++r) tsum += red[r * COUT + tid];
    atomicAdd(&statOut[tid * 8 + slot], tsum);
  }
  __syncthreads();
#pragma unroll
  for (int q = 0; q < 4; ++q) red[rg * COUT + cg * 4 + q] = s2[q];
  __syncthreads();
  if (tid < COUT) {
    float tsum = 0.f;
#pragma unroll
    for (int r = 0; r < RG; ++r) tsum += red[r * COUT + tid];
    atomicAdd(&statOut[COUT * 8 + tid * 8 + slot], tsum);
  }
}

// ---------------- fe = sum_k relu(bn(y3)) --------------------------------------
__global__ __launch_bounds__(256) void k_fe(const float* __restrict__ y3,
                                            const float* __restrict__ stat,
                                            const float* __restrict__ g,
                                            const float* __restrict__ bb,
                                            float* __restrict__ fe) {
  __shared__ float scl[C_], shf[C_];
  if (threadIdx.x < C_) {
    int c = threadIdx.x;
    float s = 0.f, s2 = 0.f;
#pragma unroll
    for (int u = 0; u < 8; ++u) {
      s += stat[c * 8 + u];
      s2 += stat[C_ * 8 + c * 8 + u];
    }
    const float invM = 1.f / (float)(B_ * N_ * K2_);
    float m = s * invM;
    float v = s2 * invM - m * m;
    float sc = g[c] * rsqrtf(v + EPS_);
    scl[c] = sc;
    shf[c] = bb[c] - m * sc;
  }
  __syncthreads();
  int t = blockIdx.x * 256 + threadIdx.x;  // over B*N*C
  int bn = t >> 6, c = t & 63;
  float s = 0.f;
#pragma unroll
  for (int k = 0; k < K2_; ++k)
    s += fmaxf(fmaf(y3[(size_t)(bn * K2_ + k) * C_ + c], scl[c], shf[c]), 0.f);
  fe[t] = s;
}

// ---------------- pooled[b][c] = sum_{n,k} relu(bn(y5)) ------------------------
__global__ __launch_bounds__(256) void k_pooled(const float* __restrict__ y5,
                                                const float* __restrict__ stat,
                                                const float* __restrict__ g,
                                                const float* __restrict__ bb,
                                                float* __restrict__ pooled) {
  __shared__ float scl[C_], shf[C_];
  __shared__ float red[4][C_];
  if (threadIdx.x < C_) {
    int c = threadIdx.x;
    float s = 0.f, s2 = 0.f;
#pragma unroll
    for (int u = 0; u < 8; ++u) {
      s += stat[c * 8 + u];
      s2 += stat[C_ * 8 + c * 8 + u];
    }
    const float invM = 1.f / (float)(B_ * N_ * K1_);
    float m = s * invM;
    float v = s2 * invM - m * m;
    float sc = g[c] * rsqrtf(v + EPS_);
    scl[c] = sc;
    shf[c] = bb[c] - m * sc;
  }
  __syncthreads();
  int c = threadIdx.x & 63;
  int rs = threadIdx.x >> 6;  // 0..3
  int row0 = blockIdx.x * 64;
  int b = row0 / (N_ * K1_);
  float s = 0.f;
  for (int i = 0; i < 16; ++i) {
    int row = row0 + rs * 16 + i;
    s += fmaxf(fmaf(y5[(size_t)row * C_ + c], scl[c], shf[c]), 0.f);
  }
  red[rs][c] = s;
  __syncthreads();
  if (threadIdx.x < C_) {
    float t2 = red[0][c] + red[1][c] + red[2][c] + red[3][c];
    atomicAdd(&pooled[(b * C_ + c) * 8 + (blockIdx.x & 7)], t2);
  }
}

// ---------------- head ---------------------------------------------------------
__global__ void k_final(const float* __restrict__ pooled, const float* __restrict__ wq,
                        const float* __restrict__ bq, const float* __restrict__ wt,
                        const float* __restrict__ bt, const float* __restrict__ qc,
                        const float* __restrict__ tc, float* __restrict__ out) {
  int b = threadIdx.x;
  if (b >= B_) return;
  float P[C_];
#pragma unroll
  for (int c = 0; c < C_; ++c) {
    float s = 0.f;
#pragma unroll
    for (int u = 0; u < 8; ++u) s += pooled[(b * C_ + c) * 8 + u];
    P[c] = s;
  }
  float qd[4];
#pragma unroll
  for (int i = 0; i < 4; ++i) {
    float s = bq[i];
#pragma unroll
    for (int c = 0; c < C_; ++c) s = fmaf(P[c], wq[i * C_ + c], s);
    qd[i] = s;
  }
  float td[3];
#pragma unroll
  for (int i = 0; i < 3; ++i) {
    float s = bt[i];
#pragma unroll
    for (int c = 0; c < C_; ++c) s = fmaf(P[c], wt[i * C_ + c], s);
    td[i] = s;
  }
  float nq = sqrtf(qd[0] * qd[0] + qd[1] * qd[1] + qd[2] * qd[2] + qd[3] * qd[3]) + 1e-10f;
#pragma unroll
  for (int i = 0; i < 4; ++i) qd[i] /= nq;
  // q_new = normalize(quat_mul(q_det, q_coarse))
  float cw = qc[b * 4 + 0], cx = qc[b * 4 + 1], cyy = qc[b * 4 + 2], cz = qc[b * 4 + 3];
  float qnw = qd[0] * cw - qd[1] * cx - qd[2] * cyy - qd[3] * cz;
  float qnx = qd[0] * cx + qd[1] * cw + qd[2] * cz - qd[3] * cyy;
  float qny = qd[0] * cyy - qd[1] * cz + qd[2] * cw + qd[3] * cx;
  float qnz = qd[0] * cz + qd[1] * cyy - qd[2] * cx + qd[3] * cw;
  float nn = sqrtf(qnw * qnw + qnx * qnx + qny * qny + qnz * qnz) + 1e-10f;
  // t_new = qrot(q_det, t_coarse) + t_det
  float vx = tc[b * 3 + 0], vy = tc[b * 3 + 1], vz = tc[b * 3 + 2];
  float aw = -(qd[1] * vx + qd[2] * vy + qd[3] * vz);
  float ax = qd[0] * vx + qd[2] * vz - qd[3] * vy;
  float ay = qd[0] * vy - qd[1] * vz + qd[3] * vx;
  float az = qd[0] * vz + qd[1] * vy - qd[2] * vx;
  float n2 = qd[0] * qd[0] + qd[1] * qd[1] + qd[2] * qd[2] + qd[3] * qd[3] + 1e-10f;
  float bw = qd[0] / n2, bx = -qd[1] / n2, by = -qd[2] / n2, bz = -qd[3] / n2;
  float rx = aw * bx + ax * bw + ay * bz - az * by;
  float ry = aw * by - ax * bz + ay * bw + az * bx;
  float rz = aw * bz + ax * by - ay * bx + az * bw;
  out[b * 7 + 0] = qnw / nn;
  out[b * 7 + 1] = qnx / nn;
  out[b * 7 + 2] = qny / nn;
  out[b * 7 + 3] = qnz / nn;
  out[b * 7 + 4] = rx + td[0];
  out[b * 7 + 5] = ry + td[1];
  out[b * 7 + 6] = rz + td[2];
}

extern "C" void kernel_launch(void* const* d_in, const int* in_sizes, int n_in,
                              void* d_out, int out_size, void* d_ws, size_t ws_size,
                              hipStream_t stream) {
  const float* pos1 = (const float*)d_in[0];
  const float* pos2 = (const float*)d_in[1];
  const float* feat1 = (const float*)d_in[2];
  const float* feat2 = (const float*)d_in[3];
  const float* qc = (const float*)d_in[4];
  const float* tc = (const float*)d_in[5];
  const float* w1_0 = (const float*)d_in[6];
  const float* g1_0 = (const float*)d_in[7];
  const float* b1_0 = (const float*)d_in[8];
  const float* w1_1 = (const float*)d_in[9];
  const float* g1_1 = (const float*)d_in[10];
  const float* b1_1 = (const float*)d_in[11];
  const float* w1_2 = (const float*)d_in[12];
  const float* g1_2 = (const float*)d_in[13];
  const float* b1_2 = (const float*)d_in[14];
  const float* w2_0 = (const float*)d_in[15];
  const float* g2_0 = (const float*)d_in[16];
  const float* b2_0 = (const float*)d_in[17];
  const float* w2_1 = (const float*)d_in[18];
  const float* g2_1 = (const float*)d_in[19];
  const float* b2_1 = (const float*)d_in[20];
  const float* wq = (const float*)d_in[21];
  const float* bq = (const float*)d_in[22];
  const float* wt = (const float*)d_in[23];
  const float* bt = (const float*)d_in[24];

  float* ws = (float*)d_ws;
  // workspace layout (float offsets); total = 22,243,328 floats = 89 MB
  const size_t off_posw = 0;                       // 49152
  const size_t off_fe = off_posw + 49152;          // 1048576
  const size_t off_stat = off_fe + 1048576;        // 8192
  const size_t off_pool = off_stat + 8192;         // 2048
  const size_t off_idx2 = off_pool + 2048;         // 98304 (int)
  const size_t off_idx1 = off_idx2 + 98304;        // 65536 (int)
  const size_t off_bufA = off_idx1 + 65536;        // 12582912
  const size_t off_bufB = off_bufA + 12582912;     // 8388608

  float* posw = ws + off_posw;
  float* fe = ws + off_fe;
  float* stat0 = ws + off_stat;        // 128*16
  float* stat1 = stat0 + 2048;         // 64*16
  float* stat2 = stat1 + 1024;         // 64*16
  float* stat3 = stat2 + 1024;         // 128*16
  float* stat4 = stat3 + 2048;         // 64*16
  float* pooled = ws + off_pool;
  int* idx2 = (int*)(ws + off_idx2);
  int* idx1 = (int*)(ws + off_idx1);
  float* bufA = ws + off_bufA;
  float* bufB = ws + off_bufB;
  // KNN scratch overlaps bufA (used strictly before the layer kernels)
  float* knnD = bufA;
  int* knnI = (int*)(bufA + 393216);

  // zero stats + pooled (ws is poisoned 0xAA before every timed launch)
  hipMemsetAsync(ws + off_stat, 0, (8192 + 2048) * sizeof(float), stream);

  k_pose<<<dim3(B_ * N_ / 256), 256, 0, stream>>>(pos1, qc, tc, posw);

  k_knn_part<K2_><<<dim3(N_ / 256, 4, B_), 256, 0, stream>>>(posw, pos2, knnD, knnI);
  k_knn_merge<K2_><<<dim3(B_ * N_ / 256), 256, 0, stream>>>(knnD, knnI, idx2);
  k_knn_part<K1_><<<dim3(N_ / 256, 4, B_), 256, 0, stream>>>(posw, posw, knnD, knnI);
  k_knn_merge<K1_><<<dim3(B_ * N_ / 256), 256, 0, stream>>>(knnD, knnI, idx1);

  // MLP1 layer 0: gather(pos2,feat2)+feat1 -> 128ch
  k_layer<131, 128, MODE_GATHER, K2_><<<dim3(98304 / 64), 256, 0, stream>>>(
      w1_0, pos2, posw, feat2, feat1, idx2, nullptr, nullptr, nullptr, nullptr, 0.f,
      bufA, stat0);
  // MLP1 layer 1
  k_layer<128, 64, MODE_PLAIN, 1><<<dim3(98304 / 64), 256, 0, stream>>>(
      w1_1, nullptr, nullptr, nullptr, nullptr, nullptr, bufA, stat0, g1_0, b1_0,
      1.f / 98304.f, bufB, stat1);
  // MLP1 layer 2
  k_layer<64, 64, MODE_PLAIN, 1><<<dim3(98304 / 64), 256, 0, stream>>>(
      w1_2, nullptr, nullptr, nullptr, nullptr, nullptr, bufB, stat1, g1_1, b1_1,
      1.f / 98304.f, bufA, stat2);
  // fe = sum_k relu(bn(y3))
  k_fe<<<dim3(B_ * N_ * C_ / 256), 256, 0, stream>>>(bufA, stat2, g1_2, b1_2, fe);
  // MLP2 layer 0: gather(pos1_w, fe)+feat1 -> 128ch
  k_layer<131, 128, MODE_GATHER, K1_><<<dim3(65536 / 64), 256, 0, stream>>>(
      w2_0, posw, posw, fe, feat1, idx1, nullptr, nullptr, nullptr, nullptr, 0.f,
      bufB, stat3);
  // MLP2 layer 1
  k_layer<128, 64, MODE_PLAIN, 1><<<dim3(65536 / 64), 256, 0, stream>>>(
      w2_1, nullptr, nullptr, nullptr, nullptr, nullptr, bufB, stat3, g2_0, b2_0,
      1.f / 65536.f, bufA, stat4);
  // pooled
  k_pooled<<<dim3(65536 / 64), 256, 0, stream>>>(bufA, stat4, g2_1, b2_1, pooled);
  // head
  k_final<<<dim3(1), 64, 0, stream>>>(pooled, wq, bq, wt, bt, qc, tc, (float*)d_out);
}

// Round 2
// 641.890 us; speedup vs baseline: 1.5754x; 1.5754x over previous
//
#include <hip/hip_runtime.h>
#include <math.h>

#define B_ 4
#define N_ 4096
#define C_ 64
#define K1_ 4
#define K2_ 6
#define EPS_ 1e-5f

#define MODE_GATHER 0
#define MODE_PLAIN 2

typedef __attribute__((ext_vector_type(8))) short bf16x8;
typedef __attribute__((ext_vector_type(4))) float f32x4;

__device__ __forceinline__ unsigned short f2bf(float f) {
  unsigned int u = __float_as_uint(f);
  unsigned int r = (u + 0x7fffu + ((u >> 16) & 1u)) >> 16;
  return (unsigned short)r;
}
__device__ __forceinline__ float bf2f(unsigned short u) {
  return __uint_as_float(((unsigned int)u) << 16);
}

// ---------------- pose: pos1_w = qrot(q_coarse, pos1) + t_coarse ----------------
__global__ __launch_bounds__(256) void k_pose(const float* __restrict__ pos1,
                                              const float* __restrict__ qc,
                                              const float* __restrict__ tc,
                                              float* __restrict__ posw) {
  int t = blockIdx.x * 256 + threadIdx.x;
  if (t >= B_ * N_) return;
  int b = t / N_;
  float qw = qc[b * 4 + 0], qx = qc[b * 4 + 1], qy = qc[b * 4 + 2], qz = qc[b * 4 + 3];
  float vx = pos1[t * 3 + 0], vy = pos1[t * 3 + 1], vz = pos1[t * 3 + 2];
  float aw = -(qx * vx + qy * vy + qz * vz);
  float ax = qw * vx + qy * vz - qz * vy;
  float ay = qw * vy - qx * vz + qz * vx;
  float az = qw * vz + qx * vy - qy * vx;
  float n2 = qw * qw + qx * qx + qy * qy + qz * qz + 1e-10f;
  float bw = qw / n2, bx = -qx / n2, by = -qy / n2, bz = -qz / n2;
  float rx = aw * bx + ax * bw + ay * bz - az * by;
  float ry = aw * by - ax * bz + ay * bw + az * bx;
  float rz = aw * bz + ax * by - ay * bx + az * bw;
  posw[t * 3 + 0] = rx + tc[b * 3 + 0];
  posw[t * 3 + 1] = ry + tc[b * 3 + 1];
  posw[t * 3 + 2] = rz + tc[b * 3 + 2];
}

// ---------------- chunked KNN (stable top-k, jax tie-break = lower index) ------
template <int K>
__global__ __launch_bounds__(256) void k_knn_part(const float* __restrict__ qpos,
                                                  const float* __restrict__ ppos,
                                                  float* __restrict__ outD,
                                                  int* __restrict__ outI) {
  __shared__ float4 pts[1024];
  int b = blockIdx.z;
  int cy = blockIdx.y;
  int base = cy * 1024;
  for (int i = threadIdx.x; i < 1024; i += 256) {
    const float* p = ppos + (size_t)(b * N_ + base + i) * 3;
    float x = p[0], y = p[1], z = p[2];
    pts[i] = make_float4(x, y, z, x * x + y * y + z * z);
  }
  __syncthreads();
  int n = blockIdx.x * 256 + threadIdx.x;
  const float* q = qpos + (size_t)(b * N_ + n) * 3;
  float qx = q[0], qy = q[1], qz = q[2];
  float qq = qx * qx + qy * qy + qz * qz;
  float bd[K];
  int bi[K];
#pragma unroll
  for (int t = 0; t < K; ++t) { bd[t] = INFINITY; bi[t] = 0x7fffffff; }
  for (int j = 0; j < 1024; ++j) {
    float4 p = pts[j];
    float d = qq + p.w - 2.f * (qx * p.x + qy * p.y + qz * p.z);
    if (d < bd[K - 1]) {
      int pos = 0;
#pragma unroll
      for (int t = 0; t < K - 1; ++t) pos += (bd[t] <= d) ? 1 : 0;
#pragma unroll
      for (int u = K - 1; u > 0; --u) {
        bool mv = (u > pos);
        bd[u] = mv ? bd[u - 1] : bd[u];
        bi[u] = mv ? bi[u - 1] : bi[u];
      }
#pragma unroll
      for (int u = 0; u < K; ++u) {
        if (u == pos) { bd[u] = d; bi[u] = base + j; }
      }
    }
  }
  size_t ob = ((size_t)(b * N_ + n) * 4 + cy) * K;
#pragma unroll
  for (int t = 0; t < K; ++t) { outD[ob + t] = bd[t]; outI[ob + t] = bi[t]; }
}

template <int K>
__global__ __launch_bounds__(256) void k_knn_merge(const float* __restrict__ inD,
                                                   const int* __restrict__ inI,
                                                   int* __restrict__ idx) {
  int t = blockIdx.x * 256 + threadIdx.x;
  if (t >= B_ * N_) return;
  float bd[K];
  int bi[K];
#pragma unroll
  for (int u = 0; u < K; ++u) { bd[u] = INFINITY; bi[u] = 0x7fffffff; }
  size_t ib = (size_t)t * 4 * K;
  for (int c = 0; c < 4 * K; ++c) {
    float d = inD[ib + c];
    int j = inI[ib + c];
    if (d < bd[K - 1]) {
      int pos = 0;
#pragma unroll
      for (int u = 0; u < K - 1; ++u) pos += (bd[u] <= d) ? 1 : 0;
#pragma unroll
      for (int u = K - 1; u > 0; --u) {
        bool mv = (u > pos);
        bd[u] = mv ? bd[u - 1] : bd[u];
        bi[u] = mv ? bi[u - 1] : bi[u];
      }
#pragma unroll
      for (int u = 0; u < K; ++u) {
        if (u == pos) { bd[u] = d; bi[u] = j; }
      }
    }
  }
#pragma unroll
  for (int u = 0; u < K; ++u) idx[(size_t)t * K + u] = bi[u];
}

// ---------------- weight pre-conversion to bf16 (padded, permuted) -------------
// gather layers use channel order [featN(64) | feat1(64) | xyz(3) | pad] so the
// X staging is pure float4; W column c maps: k<128 -> c=k+3; 128<=k<131 -> k-128.
__global__ __launch_bounds__(256) void k_wconv_all(
    const float* __restrict__ W0, const float* __restrict__ W1,
    const float* __restrict__ W2, const float* __restrict__ W3,
    const float* __restrict__ W4, unsigned short* __restrict__ O0,
    unsigned short* __restrict__ O1, unsigned short* __restrict__ O2,
    unsigned short* __restrict__ O3, unsigned short* __restrict__ O4) {
  int m = blockIdx.y;
  const float* W;
  unsigned short* O;
  int COUT, CIN, KP, perm;
  switch (m) {
    case 0: W = W0; O = O0; COUT = 128; CIN = 131; KP = 160; perm = 1; break;
    case 1: W = W1; O = O1; COUT = 64; CIN = 128; KP = 128; perm = 0; break;
    case 2: W = W2; O = O2; COUT = 64; CIN = 64; KP = 64; perm = 0; break;
    case 3: W = W3; O = O3; COUT = 128; CIN = 131; KP = 160; perm = 1; break;
    default: W = W4; O = O4; COUT = 64; CIN = 128; KP = 128; perm = 0; break;
  }
  int t = blockIdx.x * 256 + threadIdx.x;
  if (t >= COUT * KP) return;
  int o = t / KP, k = t - o * KP;
  float v = 0.f;
  if (perm) {
    int c = (k < 128) ? (k + 3) : (k < 131) ? (k - 128) : -1;
    if (c >= 0) v = W[o * CIN + c];
  } else if (k < CIN) {
    v = W[o * CIN + k];
  }
  O[t] = f2bf(v);
}

// ---------------- fused gather/BN-relu + bf16-MFMA GEMM layer ------------------
// y[row][o] = sum_c x[row][c] * W[o][c]; fp32 accumulate; per-channel stats.
template <int CIN, int COUT, int KP, int MODE, int KNN>
__global__ __launch_bounds__(256) void k_layer_mfma(
    const unsigned short* __restrict__ Wb,  // [COUT][KP] bf16
    const float* __restrict__ posP, const float* __restrict__ posQ,
    const float* __restrict__ featN, const float* __restrict__ feat1,
    const int* __restrict__ idx,
    const unsigned short* __restrict__ yprev,  // [rows][CIN] bf16 (PLAIN mode)
    const float* __restrict__ statPrev, const float* __restrict__ gPrev,
    const float* __restrict__ bPrev, float prevInvM,
    unsigned short* __restrict__ yout,  // [rows][COUT] bf16
    float* __restrict__ statOut) {
  constexpr int SP = KP + 8;    // LDS row stride (bf16) -> <=2-way bank aliasing
  constexpr int CST = COUT + 8; // epilogue restage stride
  constexpr int CT = COUT / 64; // col tiles per wave (16 cols each)
  __shared__ unsigned short Xs[64 * SP];
  __shared__ float scl[CIN];
  __shared__ float shf[CIN];

  int tid = threadIdx.x;
  int row0 = blockIdx.x * 64;

  if (MODE == MODE_PLAIN) {
    for (int c = tid; c < CIN; c += 256) {
      float s = 0.f, s2 = 0.f;
#pragma unroll
      for (int u = 0; u < 8; ++u) {
        s += statPrev[c * 8 + u];
        s2 += statPrev[CIN * 8 + c * 8 + u];
      }
      float m = s * prevInvM;
      float v = s2 * prevInvM - m * m;
      float sc = gPrev[c] * rsqrtf(v + EPS_);
      scl[c] = sc;
      shf[c] = bPrev[c] - m * sc;
    }
    __syncthreads();
    constexpr int S4 = KP / 4;
    for (int e = tid; e < 64 * S4; e += 256) {
      int r = e / S4, s = e - r * S4;
      int row = row0 + r;
      ushort4 u = *(const ushort4*)&yprev[(size_t)row * CIN + s * 4];
      ushort4 o;
      o.x = f2bf(fmaxf(fmaf(bf2f(u.x), scl[s * 4 + 0], shf[s * 4 + 0]), 0.f));
      o.y = f2bf(fmaxf(fmaf(bf2f(u.y), scl[s * 4 + 1], shf[s * 4 + 1]), 0.f));
      o.z = f2bf(fmaxf(fmaf(bf2f(u.z), scl[s * 4 + 2], shf[s * 4 + 2]), 0.f));
      o.w = f2bf(fmaxf(fmaf(bf2f(u.w), scl[s * 4 + 3], shf[s * 4 + 3]), 0.f));
      *(ushort4*)&Xs[r * SP + s * 4] = o;
    }
  } else {
    constexpr int S4 = KP / 4;  // 40 segments of 4 channels
    for (int e = tid; e < 64 * S4; e += 256) {
      int r = e / S4, s = e - r * S4;
      int row = row0 + r;
      int b = row / (N_ * KNN);
      int rem = row - b * (N_ * KNN);
      int n = rem / KNN;
      float4 v = make_float4(0.f, 0.f, 0.f, 0.f);
      if (s < 16) {
        int j = idx[row];
        v = *(const float4*)&featN[((size_t)(b * N_ + j)) * C_ + s * 4];
      } else if (s < 32) {
        v = *(const float4*)&feat1[((size_t)(b * N_ + n)) * C_ + (s - 16) * 4];
      } else if (s == 32) {
        int j = idx[row];
        const float* pp = &posP[(size_t)(b * N_ + j) * 3];
        const float* pq = &posQ[(size_t)(b * N_ + n) * 3];
        v = make_float4(pp[0] - pq[0], pp[1] - pq[1], pp[2] - pq[2], 0.f);
      }
      ushort4 o;
      o.x = f2bf(v.x); o.y = f2bf(v.y); o.z = f2bf(v.z); o.w = f2bf(v.w);
      *(ushort4*)&Xs[r * SP + s * 4] = o;
    }
  }
  __syncthreads();

  int l = tid & 63, wv = tid >> 6;
  int lm = l & 15, quad = l >> 4;
  int n0 = wv * (COUT / 4);

  f32x4 acc[4][CT];
#pragma unroll
  for (int rt = 0; rt < 4; ++rt)
#pragma unroll
    for (int ct = 0; ct < CT; ++ct) acc[rt][ct] = (f32x4)(0.f);

#pragma unroll
  for (int k0 = 0; k0 < KP; k0 += 32) {
    bf16x8 a[4], b[CT];
#pragma unroll
    for (int rt = 0; rt < 4; ++rt)
      a[rt] = *(const bf16x8*)&Xs[(rt * 16 + lm) * SP + k0 + quad * 8];
#pragma unroll
    for (int ct = 0; ct < CT; ++ct)
      b[ct] = *(const bf16x8*)&Wb[(size_t)(n0 + ct * 16 + lm) * KP + k0 + quad * 8];
#pragma unroll
    for (int rt = 0; rt < 4; ++rt)
#pragma unroll
      for (int ct = 0; ct < CT; ++ct)
        acc[rt][ct] =
            __builtin_amdgcn_mfma_f32_16x16x32_bf16(a[rt], b[ct], acc[rt][ct], 0, 0, 0);
  }

  // BN statistics: reduce this lane's 16 rows, then across quads, one atomic/col
  int slot = blockIdx.x & 7;
#pragma unroll
  for (int ct = 0; ct < CT; ++ct) {
    float s1 = 0.f, s2 = 0.f;
#pragma unroll
    for (int rt = 0; rt < 4; ++rt)
#pragma unroll
      for (int r = 0; r < 4; ++r) {
        float v = acc[rt][ct][r];
        s1 += v;
        s2 += v * v;
      }
    s1 += __shfl_xor(s1, 16);
    s1 += __shfl_xor(s1, 32);
    s2 += __shfl_xor(s2, 16);
    s2 += __shfl_xor(s2, 32);
    if (quad == 0) {
      int col = n0 + ct * 16 + lm;
      atomicAdd(&statOut[col * 8 + slot], s1);
      atomicAdd(&statOut[COUT * 8 + col * 8 + slot], s2);
    }
  }

  // restage D through LDS (bf16) for 16B-coalesced global stores
  __syncthreads();
  unsigned short* Ys = Xs;
#pragma unroll
  for (int rt = 0; rt < 4; ++rt)
#pragma unroll
    for (int ct = 0; ct < CT; ++ct)
#pragma unroll
      for (int r = 0; r < 4; ++r)
        Ys[(rt * 16 + quad * 4 + r) * CST + n0 + ct * 16 + lm] = f2bf(acc[rt][ct][r]);
  __syncthreads();
  constexpr int S8 = COUT / 8;
  for (int e = tid; e < 64 * S8; e += 256) {
    int r = e / S8, c0 = (e - r * S8) * 8;
    uint4 v = *(const uint4*)&Ys[r * CST + c0];
    *(uint4*)&yout[((size_t)(row0 + r)) * COUT + c0] = v;
  }
}

// ---------------- fe = sum_k relu(bn(y3)), fp32 out ----------------------------
__global__ __launch_bounds__(256) void k_fe(const unsigned short* __restrict__ y3,
                                            const float* __restrict__ stat,
                                            const float* __restrict__ g,
                                            const float* __restrict__ bb,
                                            float* __restrict__ fe) {
  __shared__ float scl[C_], shf[C_];
  if (threadIdx.x < C_) {
    int c = threadIdx.x;
    float s = 0.f, s2 = 0.f;
#pragma unroll
    for (int u = 0; u < 8; ++u) {
      s += stat[c * 8 + u];
      s2 += stat[C_ * 8 + c * 8 + u];
    }
    const float invM = 1.f / (float)(B_ * N_ * K2_);
    float m = s * invM;
    float v = s2 * invM - m * m;
    float sc = g[c] * rsqrtf(v + EPS_);
    scl[c] = sc;
    shf[c] = bb[c] - m * sc;
  }
  __syncthreads();
  int t = blockIdx.x * 256 + threadIdx.x;  // over B*N*C
  int bn = t >> 6, c = t & 63;
  float s = 0.f;
#pragma unroll
  for (int k = 0; k < K2_; ++k)
    s += fmaxf(fmaf(bf2f(y3[(size_t)(bn * K2_ + k) * C_ + c]), scl[c], shf[c]), 0.f);
  fe[t] = s;
}

// ---------------- pooled[b][c] = sum_{n,k} relu(bn(y5)) ------------------------
__global__ __launch_bounds__(256) void k_pooled(const unsigned short* __restrict__ y5,
                                                const float* __restrict__ stat,
                                                const float* __restrict__ g,
                                                const float* __restrict__ bb,
                                                float* __restrict__ pooled) {
  __shared__ float scl[C_], shf[C_];
  __shared__ float red[4][C_];
  if (threadIdx.x < C_) {
    int c = threadIdx.x;
    float s = 0.f, s2 = 0.f;
#pragma unroll
    for (int u = 0; u < 8; ++u) {
      s += stat[c * 8 + u];
      s2 += stat[C_ * 8 + c * 8 + u];
    }
    const float invM = 1.f / (float)(B_ * N_ * K1_);
    float m = s * invM;
    float v = s2 * invM - m * m;
    float sc = g[c] * rsqrtf(v + EPS_);
    scl[c] = sc;
    shf[c] = bb[c] - m * sc;
  }
  __syncthreads();
  int c = threadIdx.x & 63;
  int rs = threadIdx.x >> 6;
  int row0 = blockIdx.x * 64;
  int b = row0 / (N_ * K1_);
  float s = 0.f;
  for (int i = 0; i < 16; ++i) {
    int row = row0 + rs * 16 + i;
    s += fmaxf(fmaf(bf2f(y5[(size_t)row * C_ + c]), scl[c], shf[c]), 0.f);
  }
  red[rs][c] = s;
  __syncthreads();
  if (threadIdx.x < C_) {
    float t2 = red[0][c] + red[1][c] + red[2][c] + red[3][c];
    atomicAdd(&pooled[(b * C_ + c) * 8 + (blockIdx.x & 7)], t2);
  }
}

// ---------------- head ---------------------------------------------------------
__global__ void k_final(const float* __restrict__ pooled, const float* __restrict__ wq,
                        const float* __restrict__ bq, const float* __restrict__ wt,
                        const float* __restrict__ bt, const float* __restrict__ qc,
                        const float* __restrict__ tc, float* __restrict__ out) {
  int b = threadIdx.x;
  if (b >= B_) return;
  float P[C_];
#pragma unroll
  for (int c = 0; c < C_; ++c) {
    float s = 0.f;
#pragma unroll
    for (int u = 0; u < 8; ++u) s += pooled[(b * C_ + c) * 8 + u];
    P[c] = s;
  }
  float qd[4];
#pragma unroll
  for (int i = 0; i < 4; ++i) {
    float s = bq[i];
#pragma unroll
    for (int c = 0; c < C_; ++c) s = fmaf(P[c], wq[i * C_ + c], s);
    qd[i] = s;
  }
  float td[3];
#pragma unroll
  for (int i = 0; i < 3; ++i) {
    float s = bt[i];
#pragma unroll
    for (int c = 0; c < C_; ++c) s = fmaf(P[c], wt[i * C_ + c], s);
    td[i] = s;
  }
  float nq = sqrtf(qd[0] * qd[0] + qd[1] * qd[1] + qd[2] * qd[2] + qd[3] * qd[3]) + 1e-10f;
#pragma unroll
  for (int i = 0; i < 4; ++i) qd[i] /= nq;
  float cw = qc[b * 4 + 0], cx = qc[b * 4 + 1], cyy = qc[b * 4 + 2], cz = qc[b * 4 + 3];
  float qnw = qd[0] * cw - qd[1] * cx - qd[2] * cyy - qd[3] * cz;
  float qnx = qd[0] * cx + qd[1] * cw + qd[2] * cz - qd[3] * cyy;
  float qny = qd[0] * cyy - qd[1] * cz + qd[2] * cw + qd[3] * cx;
  float qnz = qd[0] * cz + qd[1] * cyy - qd[2] * cx + qd[3] * cw;
  float nn = sqrtf(qnw * qnw + qnx * qnx + qny * qny + qnz * qnz) + 1e-10f;
  float vx = tc[b * 3 + 0], vy = tc[b * 3 + 1], vz = tc[b * 3 + 2];
  float aw = -(qd[1] * vx + qd[2] * vy + qd[3] * vz);
  float ax = qd[0] * vx + qd[2] * vz - qd[3] * vy;
  float ay = qd[0] * vy - qd[1] * vz + qd[3] * vx;
  float az = qd[0] * vz + qd[1] * vy - qd[2] * vx;
  float n2 = qd[0] * qd[0] + qd[1] * qd[1] + qd[2] * qd[2] + qd[3] * qd[3] + 1e-10f;
  float bw = qd[0] / n2, bx = -qd[1] / n2, by = -qd[2] / n2, bz = -qd[3] / n2;
  float rx = aw * bx + ax * bw + ay * bz - az * by;
  float ry = aw * by - ax * bz + ay * bw + az * bx;
  float rz = aw * bz + ax * by - ay * bx + az * bw;
  out[b * 7 + 0] = qnw / nn;
  out[b * 7 + 1] = qnx / nn;
  out[b * 7 + 2] = qny / nn;
  out[b * 7 + 3] = qnz / nn;
  out[b * 7 + 4] = rx + td[0];
  out[b * 7 + 5] = ry + td[1];
  out[b * 7 + 6] = rz + td[2];
}

extern "C" void kernel_launch(void* const* d_in, const int* in_sizes, int n_in,
                              void* d_out, int out_size, void* d_ws, size_t ws_size,
                              hipStream_t stream) {
  const float* pos1 = (const float*)d_in[0];
  const float* pos2 = (const float*)d_in[1];
  const float* feat1 = (const float*)d_in[2];
  const float* feat2 = (const float*)d_in[3];
  const float* qc = (const float*)d_in[4];
  const float* tc = (const float*)d_in[5];
  const float* w1_0 = (const float*)d_in[6];
  const float* g1_0 = (const float*)d_in[7];
  const float* b1_0 = (const float*)d_in[8];
  const float* w1_1 = (const float*)d_in[9];
  const float* g1_1 = (const float*)d_in[10];
  const float* b1_1 = (const float*)d_in[11];
  const float* w1_2 = (const float*)d_in[12];
  const float* g1_2 = (const float*)d_in[13];
  const float* b1_2 = (const float*)d_in[14];
  const float* w2_0 = (const float*)d_in[15];
  const float* g2_0 = (const float*)d_in[16];
  const float* b2_0 = (const float*)d_in[17];
  const float* w2_1 = (const float*)d_in[18];
  const float* g2_1 = (const float*)d_in[19];
  const float* b2_1 = (const float*)d_in[20];
  const float* wq = (const float*)d_in[21];
  const float* bq = (const float*)d_in[22];
  const float* wt = (const float*)d_in[23];
  const float* bt = (const float*)d_in[24];

  float* ws = (float*)d_ws;
  // workspace layout (float offsets)
  const size_t off_posw = 0;                  // 49152
  const size_t off_fe = 49152;                // 1048576 (fp32)
  const size_t off_stat = 1097728;            // 8192
  const size_t off_pool = 1105920;            // 2048
  const size_t off_idx2 = 1107968;            // 98304 (int)
  const size_t off_idx1 = 1206272;            // 65536 (int)
  const size_t off_wb = 1271808;              // 30720 floats = 61440 bf16
  const size_t off_yA = 1302528;              // 6291456 floats = 12582912 bf16
  const size_t off_yB = 7593984;              // 3145728 floats = 6291456 bf16

  float* posw = ws + off_posw;
  float* fe = ws + off_fe;
  float* stat0 = ws + off_stat;  // 128*16
  float* stat1 = stat0 + 2048;   // 64*16
  float* stat2 = stat1 + 1024;   // 64*16
  float* stat3 = stat2 + 1024;   // 128*16
  float* stat4 = stat3 + 2048;   // 64*16
  float* pooled = ws + off_pool;
  int* idx2 = (int*)(ws + off_idx2);
  int* idx1 = (int*)(ws + off_idx1);
  unsigned short* wb0 = (unsigned short*)(ws + off_wb);  // 128x160
  unsigned short* wb1 = wb0 + 20480;                     // 64x128
  unsigned short* wb2 = wb1 + 8192;                      // 64x64
  unsigned short* wb3 = wb2 + 4096;                      // 128x160
  unsigned short* wb4 = wb3 + 20480;                     // 64x128
  unsigned short* yA = (unsigned short*)(ws + off_yA);   // up to 98304x128 bf16
  unsigned short* yB = (unsigned short*)(ws + off_yB);   // up to 98304x64 bf16
  // KNN scratch overlaps yA (used strictly before the layer kernels)
  float* knnD = (float*)yA;
  int* knnI = (int*)(knnD + 393216);

  hipMemsetAsync(ws + off_stat, 0, (8192 + 2048) * sizeof(float), stream);

  k_wconv_all<<<dim3(80, 5), 256, 0, stream>>>(w1_0, w1_1, w1_2, w2_0, w2_1, wb0, wb1,
                                               wb2, wb3, wb4);
  k_pose<<<dim3(B_ * N_ / 256), 256, 0, stream>>>(pos1, qc, tc, posw);

  k_knn_part<K2_><<<dim3(N_ / 256, 4, B_), 256, 0, stream>>>(posw, pos2, knnD, knnI);
  k_knn_merge<K2_><<<dim3(B_ * N_ / 256), 256, 0, stream>>>(knnD, knnI, idx2);
  k_knn_part<K1_><<<dim3(N_ / 256, 4, B_), 256, 0, stream>>>(posw, posw, knnD, knnI);
  k_knn_merge<K1_><<<dim3(B_ * N_ / 256), 256, 0, stream>>>(knnD, knnI, idx1);

  // MLP1 L0: gather(pos2,feat2)+feat1 -> 128ch, y into yA
  k_layer_mfma<131, 128, 160, MODE_GATHER, K2_><<<dim3(98304 / 64), 256, 0, stream>>>(
      wb0, pos2, posw, feat2, feat1, idx2, nullptr, nullptr, nullptr, nullptr, 0.f, yA,
      stat0);
  // MLP1 L1: 128->64, yA -> yB
  k_layer_mfma<128, 64, 128, MODE_PLAIN, 1><<<dim3(98304 / 64), 256, 0, stream>>>(
      wb1, nullptr, nullptr, nullptr, nullptr, nullptr, yA, stat0, g1_0, b1_0,
      1.f / 98304.f, yB, stat1);
  // MLP1 L2: 64->64, yB -> yA (region reuse)
  k_layer_mfma<64, 64, 64, MODE_PLAIN, 1><<<dim3(98304 / 64), 256, 0, stream>>>(
      wb2, nullptr, nullptr, nullptr, nullptr, nullptr, yB, stat1, g1_1, b1_1,
      1.f / 98304.f, yA, stat2);
  // fe = sum_k relu(bn(yA))
  k_fe<<<dim3(B_ * N_ * C_ / 256), 256, 0, stream>>>(yA, stat2, g1_2, b1_2, fe);
  // MLP2 L0: gather(posw, fe)+feat1 -> 128ch, into yA (fe already extracted)
  k_layer_mfma<131, 128, 160, MODE_GATHER, K1_><<<dim3(65536 / 64), 256, 0, stream>>>(
      wb3, posw, posw, fe, feat1, idx1, nullptr, nullptr, nullptr, nullptr, 0.f, yA,
      stat3);
  // MLP2 L1: 128->64, yA -> yB
  k_layer_mfma<128, 64, 128, MODE_PLAIN, 1><<<dim3(65536 / 64), 256, 0, stream>>>(
      wb4, nullptr, nullptr, nullptr, nullptr, nullptr, yA, stat3, g2_0, b2_0,
      1.f / 65536.f, yB, stat4);
  // pooled
  k_pooled<<<dim3(65536 / 64), 256, 0, stream>>>(yB, stat4, g2_1, b2_1, pooled);
  // head
  k_final<<<dim3(1), 64, 0, stream>>>(pooled, wq, bq, wt, bt, qc, tc, (float*)d_out);
}

// Round 3
// 539.328 us; speedup vs baseline: 1.8750x; 1.1902x over previous
//
#include <hip/hip_runtime.h>
#include <math.h>

#define B_ 4
#define N_ 4096
#define C_ 64
#define K1_ 4
#define K2_ 6
#define EPS_ 1e-5f
#define BN_ (B_ * N_)
#define NCH_ 8
#define CHP_ 512

#define MODE_GATHER 0
#define MODE_PLAIN 2

typedef __attribute__((ext_vector_type(8))) short bf16x8;
typedef __attribute__((ext_vector_type(4))) float f32x4;

__device__ __forceinline__ unsigned short f2bf(float f) {
  unsigned int u = __float_as_uint(f);
  unsigned int r = (u + 0x7fffu + ((u >> 16) & 1u)) >> 16;
  return (unsigned short)r;
}
__device__ __forceinline__ float bf2f(unsigned short u) {
  return __uint_as_float(((unsigned int)u) << 16);
}

// ---------------- pose: pos1_w = qrot(q_coarse, pos1) + t_coarse ----------------
__global__ __launch_bounds__(256) void k_pose(const float* __restrict__ pos1,
                                              const float* __restrict__ qc,
                                              const float* __restrict__ tc,
                                              float* __restrict__ posw) {
  int t = blockIdx.x * 256 + threadIdx.x;
  if (t >= BN_) return;
  int b = t / N_;
  float qw = qc[b * 4 + 0], qx = qc[b * 4 + 1], qy = qc[b * 4 + 2], qz = qc[b * 4 + 3];
  float vx = pos1[t * 3 + 0], vy = pos1[t * 3 + 1], vz = pos1[t * 3 + 2];
  float aw = -(qx * vx + qy * vy + qz * vz);
  float ax = qw * vx + qy * vz - qz * vy;
  float ay = qw * vy - qx * vz + qz * vx;
  float az = qw * vz + qx * vy - qy * vx;
  float n2 = qw * qw + qx * qx + qy * qy + qz * qz + 1e-10f;
  float bw = qw / n2, bx = -qx / n2, by = -qy / n2, bz = -qz / n2;
  float rx = aw * bx + ax * bw + ay * bz - az * by;
  float ry = aw * by - ax * bz + ay * bw + az * bx;
  float rz = aw * bz + ax * by - ay * bx + az * bw;
  posw[t * 3 + 0] = rx + tc[b * 3 + 0];
  posw[t * 3 + 1] = ry + tc[b * 3 + 1];
  posw[t * 3 + 2] = rz + tc[b * 3 + 2];
}

// ---------------- stable top-6 insert (jax tie-break = lower index first) ------
__device__ __forceinline__ void ins6(float (&bd)[6], int (&bi)[6], float d, int j) {
  if (d < bd[5]) {
    int pos = 0;
#pragma unroll
    for (int t = 0; t < 5; ++t) pos += (bd[t] <= d) ? 1 : 0;  // after equals: stable
#pragma unroll
    for (int u = 5; u > 0; --u) {
      bool mv = (u > pos);
      bd[u] = mv ? bd[u - 1] : bd[u];
      bi[u] = mv ? bi[u - 1] : bi[u];
    }
#pragma unroll
    for (int u = 0; u < 6; ++u) {
      if (u == pos) { bd[u] = d; bi[u] = j; }
    }
  }
}

// ---------------- fused dual-KNN, chunked (both run top-6; K1 keeps 4) ---------
// blockIdx.z: b = z&3, which = z>>2 (0: vs pos2 for idx2, 1: vs posw for idx1)
__global__ __launch_bounds__(256) void k_knn2(const float* __restrict__ posw,
                                              const float* __restrict__ pos2,
                                              float* __restrict__ outD,
                                              int* __restrict__ outI) {
  __shared__ float4 pts[CHP_];
  int b = blockIdx.z & 3;
  int which = blockIdx.z >> 2;
  const float* __restrict__ ppos = which ? posw : pos2;
  int cy = blockIdx.y;
  int base = cy * CHP_;
  for (int i = threadIdx.x; i < CHP_; i += 256) {
    const float* p = ppos + (size_t)(b * N_ + base + i) * 3;
    float x = p[0], y = p[1], z = p[2];
    pts[i] = make_float4(x, y, z, x * x + y * y + z * z);
  }
  __syncthreads();
  int n = blockIdx.x * 256 + threadIdx.x;
  const float* q = posw + (size_t)(b * N_ + n) * 3;
  float qx = q[0], qy = q[1], qz = q[2];
  float qq = qx * qx + qy * qy + qz * qz;
  float m2x = -2.f * qx, m2y = -2.f * qy, m2z = -2.f * qz;
  float bd[6];
  int bi[6];
#pragma unroll
  for (int t = 0; t < 6; ++t) { bd[t] = INFINITY; bi[t] = 0x7fffffff; }
  for (int j = 0; j < CHP_; j += 4) {
    float4 p0 = pts[j + 0], p1 = pts[j + 1], p2 = pts[j + 2], p3 = pts[j + 3];
    float d0 = qq + fmaf(m2x, p0.x, fmaf(m2y, p0.y, fmaf(m2z, p0.z, p0.w)));
    float d1 = qq + fmaf(m2x, p1.x, fmaf(m2y, p1.y, fmaf(m2z, p1.z, p1.w)));
    float d2 = qq + fmaf(m2x, p2.x, fmaf(m2y, p2.y, fmaf(m2z, p2.z, p2.w)));
    float d3 = qq + fmaf(m2x, p3.x, fmaf(m2y, p3.y, fmaf(m2z, p3.z, p3.w)));
    float dm = fminf(fminf(d0, d1), fminf(d2, d3));
    if (dm < bd[5]) {
      ins6(bd, bi, d0, base + j + 0);
      ins6(bd, bi, d1, base + j + 1);
      ins6(bd, bi, d2, base + j + 2);
      ins6(bd, bi, d3, base + j + 3);
    }
  }
  size_t ob = ((size_t)which * BN_ * NCH_ + (size_t)(b * N_ + n) * NCH_ + cy) * 6;
#pragma unroll
  for (int t = 0; t < 6; ++t) { outD[ob + t] = bd[t]; outI[ob + t] = bi[t]; }
}

__global__ __launch_bounds__(256) void k_knn2_merge(const float* __restrict__ inD,
                                                    const int* __restrict__ inI,
                                                    int* __restrict__ idx2,
                                                    int* __restrict__ idx1) {
  int t = blockIdx.x * 256 + threadIdx.x;
  if (t >= 2 * BN_) return;
  int which = (t >= BN_) ? 1 : 0;
  int qi = t - which * BN_;
  float bd[6];
  int bi[6];
#pragma unroll
  for (int u = 0; u < 6; ++u) { bd[u] = INFINITY; bi[u] = 0x7fffffff; }
  size_t ib = ((size_t)which * BN_ + qi) * NCH_ * 6;
  for (int c = 0; c < NCH_ * 6; ++c) {  // ascending chunk order -> stable
    ins6(bd, bi, inD[ib + c], inI[ib + c]);
  }
  if (which) {
#pragma unroll
    for (int u = 0; u < K1_; ++u) idx1[(size_t)qi * K1_ + u] = bi[u];
  } else {
#pragma unroll
    for (int u = 0; u < K2_; ++u) idx2[(size_t)qi * K2_ + u] = bi[u];
  }
}

// ---------------- weight pre-conversion to bf16 (padded, permuted) -------------
__global__ __launch_bounds__(256) void k_wconv_all(
    const float* __restrict__ W0, const float* __restrict__ W1,
    const float* __restrict__ W2, const float* __restrict__ W3,
    const float* __restrict__ W4, unsigned short* __restrict__ O0,
    unsigned short* __restrict__ O1, unsigned short* __restrict__ O2,
    unsigned short* __restrict__ O3, unsigned short* __restrict__ O4) {
  int m = blockIdx.y;
  const float* W;
  unsigned short* O;
  int COUT, CIN, KP, perm;
  switch (m) {
    case 0: W = W0; O = O0; COUT = 128; CIN = 131; KP = 160; perm = 1; break;
    case 1: W = W1; O = O1; COUT = 64; CIN = 128; KP = 128; perm = 0; break;
    case 2: W = W2; O = O2; COUT = 64; CIN = 64; KP = 64; perm = 0; break;
    case 3: W = W3; O = O3; COUT = 128; CIN = 131; KP = 160; perm = 1; break;
    default: W = W4; O = O4; COUT = 64; CIN = 128; KP = 128; perm = 0; break;
  }
  int t = blockIdx.x * 256 + threadIdx.x;
  if (t >= COUT * KP) return;
  int o = t / KP, k = t - o * KP;
  float v = 0.f;
  if (perm) {
    int c = (k < 128) ? (k + 3) : (k < 131) ? (k - 128) : -1;
    if (c >= 0) v = W[o * CIN + c];
  } else if (k < CIN) {
    v = W[o * CIN + k];
  }
  O[t] = f2bf(v);
}

// ---------------- fused gather/BN-relu + bf16-MFMA GEMM layer ------------------
template <int CIN, int COUT, int KP, int MODE, int KNN>
__global__ __launch_bounds__(256) void k_layer_mfma(
    const unsigned short* __restrict__ Wb,  // [COUT][KP] bf16
    const float* __restrict__ posP, const float* __restrict__ posQ,
    const float* __restrict__ featN, const float* __restrict__ feat1,
    const int* __restrict__ idx,
    const unsigned short* __restrict__ yprev,  // [rows][CIN] bf16 (PLAIN mode)
    const float* __restrict__ statPrev, const float* __restrict__ gPrev,
    const float* __restrict__ bPrev, float prevInvM,
    unsigned short* __restrict__ yout,  // [rows][COUT] bf16
    float* __restrict__ statOut) {
  constexpr int SP = KP + 8;
  constexpr int CST = COUT + 8;
  constexpr int CT = COUT / 64;
  __shared__ unsigned short Xs[64 * SP];
  __shared__ float scl[CIN];
  __shared__ float shf[CIN];

  int tid = threadIdx.x;
  int row0 = blockIdx.x * 64;

  if (MODE == MODE_PLAIN) {
    for (int c = tid; c < CIN; c += 256) {
      float s = 0.f, s2 = 0.f;
#pragma unroll
      for (int u = 0; u < 8; ++u) {
        s += statPrev[c * 8 + u];
        s2 += statPrev[CIN * 8 + c * 8 + u];
      }
      float m = s * prevInvM;
      float v = s2 * prevInvM - m * m;
      float sc = gPrev[c] * rsqrtf(v + EPS_);
      scl[c] = sc;
      shf[c] = bPrev[c] - m * sc;
    }
    __syncthreads();
    constexpr int S4 = KP / 4;
    for (int e = tid; e < 64 * S4; e += 256) {
      int r = e / S4, s = e - r * S4;
      int row = row0 + r;
      ushort4 u = *(const ushort4*)&yprev[(size_t)row * CIN + s * 4];
      ushort4 o;
      o.x = f2bf(fmaxf(fmaf(bf2f(u.x), scl[s * 4 + 0], shf[s * 4 + 0]), 0.f));
      o.y = f2bf(fmaxf(fmaf(bf2f(u.y), scl[s * 4 + 1], shf[s * 4 + 1]), 0.f));
      o.z = f2bf(fmaxf(fmaf(bf2f(u.z), scl[s * 4 + 2], shf[s * 4 + 2]), 0.f));
      o.w = f2bf(fmaxf(fmaf(bf2f(u.w), scl[s * 4 + 3], shf[s * 4 + 3]), 0.f));
      *(ushort4*)&Xs[r * SP + s * 4] = o;
    }
  } else {
    constexpr int S4 = KP / 4;
    for (int e = tid; e < 64 * S4; e += 256) {
      int r = e / S4, s = e - r * S4;
      int row = row0 + r;
      int b = row / (N_ * KNN);
      int rem = row - b * (N_ * KNN);
      int n = rem / KNN;
      float4 v = make_float4(0.f, 0.f, 0.f, 0.f);
      if (s < 16) {
        int j = idx[row];
        v = *(const float4*)&featN[((size_t)(b * N_ + j)) * C_ + s * 4];
      } else if (s < 32) {
        v = *(const float4*)&feat1[((size_t)(b * N_ + n)) * C_ + (s - 16) * 4];
      } else if (s == 32) {
        int j = idx[row];
        const float* pp = &posP[(size_t)(b * N_ + j) * 3];
        const float* pq = &posQ[(size_t)(b * N_ + n) * 3];
        v = make_float4(pp[0] - pq[0], pp[1] - pq[1], pp[2] - pq[2], 0.f);
      }
      ushort4 o;
      o.x = f2bf(v.x); o.y = f2bf(v.y); o.z = f2bf(v.z); o.w = f2bf(v.w);
      *(ushort4*)&Xs[r * SP + s * 4] = o;
    }
  }
  __syncthreads();

  int l = tid & 63, wv = tid >> 6;
  int lm = l & 15, quad = l >> 4;
  int n0 = wv * (COUT / 4);

  f32x4 acc[4][CT];
#pragma unroll
  for (int rt = 0; rt < 4; ++rt)
#pragma unroll
    for (int ct = 0; ct < CT; ++ct) acc[rt][ct] = (f32x4)(0.f);

#pragma unroll
  for (int k0 = 0; k0 < KP; k0 += 32) {
    bf16x8 a[4], b[CT];
#pragma unroll
    for (int rt = 0; rt < 4; ++rt)
      a[rt] = *(const bf16x8*)&Xs[(rt * 16 + lm) * SP + k0 + quad * 8];
#pragma unroll
    for (int ct = 0; ct < CT; ++ct)
      b[ct] = *(const bf16x8*)&Wb[(size_t)(n0 + ct * 16 + lm) * KP + k0 + quad * 8];
#pragma unroll
    for (int rt = 0; rt < 4; ++rt)
#pragma unroll
      for (int ct = 0; ct < CT; ++ct)
        acc[rt][ct] =
            __builtin_amdgcn_mfma_f32_16x16x32_bf16(a[rt], b[ct], acc[rt][ct], 0, 0, 0);
  }

  int slot = blockIdx.x & 7;
#pragma unroll
  for (int ct = 0; ct < CT; ++ct) {
    float s1 = 0.f, s2 = 0.f;
#pragma unroll
    for (int rt = 0; rt < 4; ++rt)
#pragma unroll
      for (int r = 0; r < 4; ++r) {
        float v = acc[rt][ct][r];
        s1 += v;
        s2 += v * v;
      }
    s1 += __shfl_xor(s1, 16);
    s1 += __shfl_xor(s1, 32);
    s2 += __shfl_xor(s2, 16);
    s2 += __shfl_xor(s2, 32);
    if (quad == 0) {
      int col = n0 + ct * 16 + lm;
      atomicAdd(&statOut[col * 8 + slot], s1);
      atomicAdd(&statOut[COUT * 8 + col * 8 + slot], s2);
    }
  }

  __syncthreads();
  unsigned short* Ys = Xs;
#pragma unroll
  for (int rt = 0; rt < 4; ++rt)
#pragma unroll
    for (int ct = 0; ct < CT; ++ct)
#pragma unroll
      for (int r = 0; r < 4; ++r)
        Ys[(rt * 16 + quad * 4 + r) * CST + n0 + ct * 16 + lm] = f2bf(acc[rt][ct][r]);
  __syncthreads();
  constexpr int S8 = COUT / 8;
  for (int e = tid; e < 64 * S8; e += 256) {
    int r = e / S8, c0 = (e - r * S8) * 8;
    uint4 v = *(const uint4*)&Ys[r * CST + c0];
    *(uint4*)&yout[((size_t)(row0 + r)) * COUT + c0] = v;
  }
}

// ---------------- fe = sum_k relu(bn(y3)), fp32 out ----------------------------
__global__ __launch_bounds__(256) void k_fe(const unsigned short* __restrict__ y3,
                                            const float* __restrict__ stat,
                                            const float* __restrict__ g,
                                            const float* __restrict__ bb,
                                            float* __restrict__ fe) {
  __shared__ float scl[C_], shf[C_];
  if (threadIdx.x < C_) {
    int c = threadIdx.x;
    float s = 0.f, s2 = 0.f;
#pragma unroll
    for (int u = 0; u < 8; ++u) {
      s += stat[c * 8 + u];
      s2 += stat[C_ * 8 + c * 8 + u];
    }
    const float invM = 1.f / (float)(BN_ * K2_);
    float m = s * invM;
    float v = s2 * invM - m * m;
    float sc = g[c] * rsqrtf(v + EPS_);
    scl[c] = sc;
    shf[c] = bb[c] - m * sc;
  }
  __syncthreads();
  int t = blockIdx.x * 256 + threadIdx.x;
  int bn = t >> 6, c = t & 63;
  float s = 0.f;
#pragma unroll
  for (int k = 0; k < K2_; ++k)
    s += fmaxf(fmaf(bf2f(y3[(size_t)(bn * K2_ + k) * C_ + c]), scl[c], shf[c]), 0.f);
  fe[t] = s;
}

// ---------------- pooled[b][c] = sum_{n,k} relu(bn(y5)) ------------------------
__global__ __launch_bounds__(256) void k_pooled(const unsigned short* __restrict__ y5,
                                                const float* __restrict__ stat,
                                                const float* __restrict__ g,
                                                const float* __restrict__ bb,
                                                float* __restrict__ pooled) {
  __shared__ float scl[C_], shf[C_];
  __shared__ float red[4][C_];
  if (threadIdx.x < C_) {
    int c = threadIdx.x;
    float s = 0.f, s2 = 0.f;
#pragma unroll
    for (int u = 0; u < 8; ++u) {
      s += stat[c * 8 + u];
      s2 += stat[C_ * 8 + c * 8 + u];
    }
    const float invM = 1.f / (float)(BN_ * K1_);
    float m = s * invM;
    float v = s2 * invM - m * m;
    float sc = g[c] * rsqrtf(v + EPS_);
    scl[c] = sc;
    shf[c] = bb[c] - m * sc;
  }
  __syncthreads();
  int c = threadIdx.x & 63;
  int rs = threadIdx.x >> 6;
  int row0 = blockIdx.x * 64;
  int b = row0 / (N_ * K1_);
  float s = 0.f;
  for (int i = 0; i < 16; ++i) {
    int row = row0 + rs * 16 + i;
    s += fmaxf(fmaf(bf2f(y5[(size_t)row * C_ + c]), scl[c], shf[c]), 0.f);
  }
  red[rs][c] = s;
  __syncthreads();
  if (threadIdx.x < C_) {
    float t2 = red[0][c] + red[1][c] + red[2][c] + red[3][c];
    atomicAdd(&pooled[(b * C_ + c) * 8 + (blockIdx.x & 7)], t2);
  }
}

// ---------------- head ---------------------------------------------------------
__global__ void k_final(const float* __restrict__ pooled, const float* __restrict__ wq,
                        const float* __restrict__ bq, const float* __restrict__ wt,
                        const float* __restrict__ bt, const float* __restrict__ qc,
                        const float* __restrict__ tc, float* __restrict__ out) {
  int b = threadIdx.x;
  if (b >= B_) return;
  float P[C_];
#pragma unroll
  for (int c = 0; c < C_; ++c) {
    float s = 0.f;
#pragma unroll
    for (int u = 0; u < 8; ++u) s += pooled[(b * C_ + c) * 8 + u];
    P[c] = s;
  }
  float qd[4];
#pragma unroll
  for (int i = 0; i < 4; ++i) {
    float s = bq[i];
#pragma unroll
    for (int c = 0; c < C_; ++c) s = fmaf(P[c], wq[i * C_ + c], s);
    qd[i] = s;
  }
  float td[3];
#pragma unroll
  for (int i = 0; i < 3; ++i) {
    float s = bt[i];
#pragma unroll
    for (int c = 0; c < C_; ++c) s = fmaf(P[c], wt[i * C_ + c], s);
    td[i] = s;
  }
  float nq = sqrtf(qd[0] * qd[0] + qd[1] * qd[1] + qd[2] * qd[2] + qd[3] * qd[3]) + 1e-10f;
#pragma unroll
  for (int i = 0; i < 4; ++i) qd[i] /= nq;
  float cw = qc[b * 4 + 0], cx = qc[b * 4 + 1], cyy = qc[b * 4 + 2], cz = qc[b * 4 + 3];
  float qnw = qd[0] * cw - qd[1] * cx - qd[2] * cyy - qd[3] * cz;
  float qnx = qd[0] * cx + qd[1] * cw + qd[2] * cz - qd[3] * cyy;
  float qny = qd[0] * cyy - qd[1] * cz + qd[2] * cw + qd[3] * cx;
  float qnz = qd[0] * cz + qd[1] * cyy - qd[2] * cx + qd[3] * cw;
  float nn = sqrtf(qnw * qnw + qnx * qnx + qny * qny + qnz * qnz) + 1e-10f;
  float vx = tc[b * 3 + 0], vy = tc[b * 3 + 1], vz = tc[b * 3 + 2];
  float aw = -(qd[1] * vx + qd[2] * vy + qd[3] * vz);
  float ax = qd[0] * vx + qd[2] * vz - qd[3] * vy;
  float ay = qd[0] * vy - qd[1] * vz + qd[3] * vx;
  float az = qd[0] * vz + qd[1] * vy - qd[2] * vx;
  float n2 = qd[0] * qd[0] + qd[1] * qd[1] + qd[2] * qd[2] + qd[3] * qd[3] + 1e-10f;
  float bw = qd[0] / n2, bx = -qd[1] / n2, by = -qd[2] / n2, bz = -qd[3] / n2;
  float rx = aw * bx + ax * bw + ay * bz - az * by;
  float ry = aw * by - ax * bz + ay * bw + az * bx;
  float rz = aw * bz + ax * by - ay * bx + az * bw;
  out[b * 7 + 0] = qnw / nn;
  out[b * 7 + 1] = qnx / nn;
  out[b * 7 + 2] = qny / nn;
  out[b * 7 + 3] = qnz / nn;
  out[b * 7 + 4] = rx + td[0];
  out[b * 7 + 5] = ry + td[1];
  out[b * 7 + 6] = rz + td[2];
}

extern "C" void kernel_launch(void* const* d_in, const int* in_sizes, int n_in,
                              void* d_out, int out_size, void* d_ws, size_t ws_size,
                              hipStream_t stream) {
  const float* pos1 = (const float*)d_in[0];
  const float* pos2 = (const float*)d_in[1];
  const float* feat1 = (const float*)d_in[2];
  const float* feat2 = (const float*)d_in[3];
  const float* qc = (const float*)d_in[4];
  const float* tc = (const float*)d_in[5];
  const float* w1_0 = (const float*)d_in[6];
  const float* g1_0 = (const float*)d_in[7];
  const float* b1_0 = (const float*)d_in[8];
  const float* w1_1 = (const float*)d_in[9];
  const float* g1_1 = (const float*)d_in[10];
  const float* b1_1 = (const float*)d_in[11];
  const float* w1_2 = (const float*)d_in[12];
  const float* g1_2 = (const float*)d_in[13];
  const float* b1_2 = (const float*)d_in[14];
  const float* w2_0 = (const float*)d_in[15];
  const float* g2_0 = (const float*)d_in[16];
  const float* b2_0 = (const float*)d_in[17];
  const float* w2_1 = (const float*)d_in[18];
  const float* g2_1 = (const float*)d_in[19];
  const float* b2_1 = (const float*)d_in[20];
  const float* wq = (const float*)d_in[21];
  const float* bq = (const float*)d_in[22];
  const float* wt = (const float*)d_in[23];
  const float* bt = (const float*)d_in[24];

  float* ws = (float*)d_ws;
  const size_t off_posw = 0;                  // 49152
  const size_t off_fe = 49152;                // 1048576 (fp32)
  const size_t off_stat = 1097728;            // 8192
  const size_t off_pool = 1105920;            // 2048
  const size_t off_idx2 = 1107968;            // 98304 (int)
  const size_t off_idx1 = 1206272;            // 65536 (int)
  const size_t off_wb = 1271808;              // 30720 floats = 61440 bf16
  const size_t off_yA = 1302528;              // 6291456 floats = 12582912 bf16
  const size_t off_yB = 7593984;              // 3145728 floats = 6291456 bf16

  float* posw = ws + off_posw;
  float* fe = ws + off_fe;
  float* stat0 = ws + off_stat;  // 128*16
  float* stat1 = stat0 + 2048;   // 64*16
  float* stat2 = stat1 + 1024;   // 64*16
  float* stat3 = stat2 + 1024;   // 128*16
  float* stat4 = stat3 + 2048;   // 64*16
  float* pooled = ws + off_pool;
  int* idx2 = (int*)(ws + off_idx2);
  int* idx1 = (int*)(ws + off_idx1);
  unsigned short* wb0 = (unsigned short*)(ws + off_wb);  // 128x160
  unsigned short* wb1 = wb0 + 20480;                     // 64x128
  unsigned short* wb2 = wb1 + 8192;                      // 64x64
  unsigned short* wb3 = wb2 + 4096;                      // 128x160
  unsigned short* wb4 = wb3 + 20480;                     // 64x128
  unsigned short* yA = (unsigned short*)(ws + off_yA);
  unsigned short* yB = (unsigned short*)(ws + off_yB);
  // KNN scratch overlaps yA (used strictly before the layer kernels)
  // needs 2*BN*NCH*6 = 1,572,864 floats for D + same for I = 3.1M floats < 6.29M
  float* knnD = (float*)yA;
  int* knnI = (int*)(knnD + 2 * BN_ * NCH_ * 6);

  hipMemsetAsync(ws + off_stat, 0, (8192 + 2048) * sizeof(float), stream);

  k_wconv_all<<<dim3(80, 5), 256, 0, stream>>>(w1_0, w1_1, w1_2, w2_0, w2_1, wb0, wb1,
                                               wb2, wb3, wb4);
  k_pose<<<dim3(BN_ / 256), 256, 0, stream>>>(pos1, qc, tc, posw);

  // fused dual KNN: grid (16 query-blocks, 8 chunks, 4 batches x 2 KNNs)
  k_knn2<<<dim3(N_ / 256, NCH_, 2 * B_), 256, 0, stream>>>(posw, pos2, knnD, knnI);
  k_knn2_merge<<<dim3(2 * BN_ / 256), 256, 0, stream>>>(knnD, knnI, idx2, idx1);

  // MLP1 L0: gather(pos2,feat2)+feat1 -> 128ch, y into yA
  k_layer_mfma<131, 128, 160, MODE_GATHER, K2_><<<dim3(98304 / 64), 256, 0, stream>>>(
      wb0, pos2, posw, feat2, feat1, idx2, nullptr, nullptr, nullptr, nullptr, 0.f, yA,
      stat0);
  // MLP1 L1: 128->64, yA -> yB
  k_layer_mfma<128, 64, 128, MODE_PLAIN, 1><<<dim3(98304 / 64), 256, 0, stream>>>(
      wb1, nullptr, nullptr, nullptr, nullptr, nullptr, yA, stat0, g1_0, b1_0,
      1.f / 98304.f, yB, stat1);
  // MLP1 L2: 64->64, yB -> yA
  k_layer_mfma<64, 64, 64, MODE_PLAIN, 1><<<dim3(98304 / 64), 256, 0, stream>>>(
      wb2, nullptr, nullptr, nullptr, nullptr, nullptr, yB, stat1, g1_1, b1_1,
      1.f / 98304.f, yA, stat2);
  // fe = sum_k relu(bn(yA))
  k_fe<<<dim3(BN_ * C_ / 256), 256, 0, stream>>>(yA, stat2, g1_2, b1_2, fe);
  // MLP2 L0: gather(posw, fe)+feat1 -> 128ch, into yA
  k_layer_mfma<131, 128, 160, MODE_GATHER, K1_><<<dim3(65536 / 64), 256, 0, stream>>>(
      wb3, posw, posw, fe, feat1, idx1, nullptr, nullptr, nullptr, nullptr, 0.f, yA,
      stat3);
  // MLP2 L1: 128->64, yA -> yB
  k_layer_mfma<128, 64, 128, MODE_PLAIN, 1><<<dim3(65536 / 64), 256, 0, stream>>>(
      wb4, nullptr, nullptr, nullptr, nullptr, nullptr, yA, stat3, g2_0, b2_0,
      1.f / 65536.f, yB, stat4);
  // pooled
  k_pooled<<<dim3(65536 / 64), 256, 0, stream>>>(yB, stat4, g2_1, b2_1, pooled);
  // head
  k_final<<<dim3(1), 64, 0, stream>>>(pooled, wq, bq, wt, bt, qc, tc, (float*)d_out);
}

// Round 4
// 467.599 us; speedup vs baseline: 2.1626x; 1.1534x over previous
//
#include <hip/hip_runtime.h>
#include <math.h>

#define B_ 4
#define N_ 4096
#define C_ 64
#define K1_ 4
#define K2_ 6
#define EPS_ 1e-5f
#define BN_ (B_ * N_)
#define NCH_ 8
#define CHP_ 512
#define STKD_ 16

#define MODE_GATHER 0
#define MODE_PLAIN 2

typedef __attribute__((ext_vector_type(8))) short bf16x8;
typedef __attribute__((ext_vector_type(4))) float f32x4;

__device__ __forceinline__ unsigned short f2bf(float f) {
  unsigned int u = __float_as_uint(f);
  unsigned int r = (u + 0x7fffu + ((u >> 16) & 1u)) >> 16;
  return (unsigned short)r;
}
__device__ __forceinline__ float bf2f(unsigned short u) {
  return __uint_as_float(((unsigned int)u) << 16);
}

// ---------------- pose + point-table build -------------------------------------
// pos1_w = qrot(q_coarse,pos1)+t; also emits (x,y,z,|p|^2) tables for both KNN
// target sets (pos2 and pos1_w) so the KNN kernel needs no LDS point staging.
__global__ __launch_bounds__(256) void k_pose(const float* __restrict__ pos1,
                                              const float* __restrict__ pos2,
                                              const float* __restrict__ qc,
                                              const float* __restrict__ tc,
                                              float* __restrict__ posw,
                                              float4* __restrict__ pts4w,
                                              float4* __restrict__ pts4p) {
  int t = blockIdx.x * 256 + threadIdx.x;
  if (t >= BN_) return;
  int b = t / N_;
  float qw = qc[b * 4 + 0], qx = qc[b * 4 + 1], qy = qc[b * 4 + 2], qz = qc[b * 4 + 3];
  float vx = pos1[t * 3 + 0], vy = pos1[t * 3 + 1], vz = pos1[t * 3 + 2];
  float aw = -(qx * vx + qy * vy + qz * vz);
  float ax = qw * vx + qy * vz - qz * vy;
  float ay = qw * vy - qx * vz + qz * vx;
  float az = qw * vz + qx * vy - qy * vx;
  float n2 = qw * qw + qx * qx + qy * qy + qz * qz + 1e-10f;
  float bw = qw / n2, bx = -qx / n2, by = -qy / n2, bz = -qz / n2;
  float rx = aw * bx + ax * bw + ay * bz - az * by;
  float ry = aw * by - ax * bz + ay * bw + az * bx;
  float rz = aw * bz + ax * by - ay * bx + az * bw;
  rx += tc[b * 3 + 0];
  ry += tc[b * 3 + 1];
  rz += tc[b * 3 + 2];
  posw[t * 3 + 0] = rx;
  posw[t * 3 + 1] = ry;
  posw[t * 3 + 2] = rz;
  pts4w[t] = make_float4(rx, ry, rz, rx * rx + ry * ry + rz * rz);
  float px = pos2[t * 3 + 0], py = pos2[t * 3 + 1], pz = pos2[t * 3 + 2];
  pts4p[t] = make_float4(px, py, pz, px * px + py * py + pz * pz);
}

// ---------------- stable top-6 insert (jax tie-break = lower index first) ------
__device__ __forceinline__ void ins6(float (&bd)[6], int (&bi)[6], float d, int j) {
  if (d < bd[5]) {
    int pos = 0;
#pragma unroll
    for (int t = 0; t < 5; ++t) pos += (bd[t] <= d) ? 1 : 0;  // after equals: stable
#pragma unroll
    for (int u = 5; u > 0; --u) {
      bool mv = (u > pos);
      bd[u] = mv ? bd[u - 1] : bd[u];
      bi[u] = mv ? bi[u - 1] : bi[u];
    }
#pragma unroll
    for (int u = 0; u < 6; ++u) {
      if (u == pos) { bd[u] = d; bi[u] = j; }
    }
  }
}

// ---------------- fused dual-KNN with LDS candidate stacks ---------------------
// blockIdx.z: b = z&3, which = z>>2 (0: vs pos2 for idx2, 1: vs posw for idx1)
// Per point: branchless distance + conditional stack push (stale threshold).
// Ballot-gated drain replays stacks through exact stable ins6 -> identical
// results to direct ins6 on every point (stale threshold accepts a superset).
__global__ __launch_bounds__(256) void k_knn2(const float4* __restrict__ pts4w,
                                              const float4* __restrict__ pts4p,
                                              float* __restrict__ outD,
                                              int* __restrict__ outI) {
  __shared__ float2 st[STKD_][256];
  int tid = threadIdx.x;
  int b = blockIdx.z & 3;
  int which = blockIdx.z >> 2;
  const float4* __restrict__ pp = (which ? pts4w : pts4p) + (size_t)b * N_;
  int base = blockIdx.y * CHP_;
  int n = blockIdx.x * 256 + tid;
  float4 qv = pts4w[(size_t)b * N_ + n];
  float qq = qv.w;
  float m2x = -2.f * qv.x, m2y = -2.f * qv.y, m2z = -2.f * qv.z;
  float bd[6];
  int bi[6];
#pragma unroll
  for (int t = 0; t < 6; ++t) { bd[t] = INFINITY; bi[t] = 0x7fffffff; }
  float bd5 = INFINITY;
  int ptr = 0;
  for (int j = 0; j < CHP_; j += 4) {
    float4 p0 = pp[base + j + 0];
    float4 p1 = pp[base + j + 1];
    float4 p2 = pp[base + j + 2];
    float4 p3 = pp[base + j + 3];
    float d0 = qq + fmaf(m2x, p0.x, fmaf(m2y, p0.y, fmaf(m2z, p0.z, p0.w)));
    float d1 = qq + fmaf(m2x, p1.x, fmaf(m2y, p1.y, fmaf(m2z, p1.z, p1.w)));
    float d2 = qq + fmaf(m2x, p2.x, fmaf(m2y, p2.y, fmaf(m2z, p2.z, p2.w)));
    float d3 = qq + fmaf(m2x, p3.x, fmaf(m2y, p3.y, fmaf(m2z, p3.z, p3.w)));
    st[ptr][tid] = make_float2(d0, __int_as_float(base + j + 0));
    ptr += (d0 < bd5) ? 1 : 0;
    st[ptr][tid] = make_float2(d1, __int_as_float(base + j + 1));
    ptr += (d1 < bd5) ? 1 : 0;
    st[ptr][tid] = make_float2(d2, __int_as_float(base + j + 2));
    ptr += (d2 < bd5) ? 1 : 0;
    st[ptr][tid] = make_float2(d3, __int_as_float(base + j + 3));
    ptr += (d3 < bd5) ? 1 : 0;
    if (__ballot(ptr >= STKD_ - 4)) {
      for (int i = 0; i < ptr; ++i) {
        float2 c = st[i][tid];
        ins6(bd, bi, c.x, __float_as_int(c.y));
      }
      ptr = 0;
      bd5 = bd[5];
    }
  }
  for (int i = 0; i < ptr; ++i) {
    float2 c = st[i][tid];
    ins6(bd, bi, c.x, __float_as_int(c.y));
  }
  size_t ob = ((size_t)which * BN_ * NCH_ + (size_t)(b * N_ + n) * NCH_ + blockIdx.y) * 6;
#pragma unroll
  for (int t = 0; t < 6; ++t) { outD[ob + t] = bd[t]; outI[ob + t] = bi[t]; }
}

__global__ __launch_bounds__(256) void k_knn2_merge(const float* __restrict__ inD,
                                                    const int* __restrict__ inI,
                                                    int* __restrict__ idx2,
                                                    int* __restrict__ idx1) {
  int t = blockIdx.x * 256 + threadIdx.x;
  if (t >= 2 * BN_) return;
  int which = (t >= BN_) ? 1 : 0;
  int qi = t - which * BN_;
  float bd[6];
  int bi[6];
#pragma unroll
  for (int u = 0; u < 6; ++u) { bd[u] = INFINITY; bi[u] = 0x7fffffff; }
  size_t ib = ((size_t)which * BN_ + qi) * NCH_ * 6;
  for (int c = 0; c < NCH_ * 6; ++c) {  // ascending chunk order -> stable
    ins6(bd, bi, inD[ib + c], inI[ib + c]);
  }
  if (which) {
#pragma unroll
    for (int u = 0; u < K1_; ++u) idx1[(size_t)qi * K1_ + u] = bi[u];
  } else {
#pragma unroll
    for (int u = 0; u < K2_; ++u) idx2[(size_t)qi * K2_ + u] = bi[u];
  }
}

// ---------------- weight pre-conversion to bf16 (padded, permuted) -------------
__global__ __launch_bounds__(256) void k_wconv_all(
    const float* __restrict__ W0, const float* __restrict__ W1,
    const float* __restrict__ W2, const float* __restrict__ W3,
    const float* __restrict__ W4, unsigned short* __restrict__ O0,
    unsigned short* __restrict__ O1, unsigned short* __restrict__ O2,
    unsigned short* __restrict__ O3, unsigned short* __restrict__ O4) {
  int m = blockIdx.y;
  const float* W;
  unsigned short* O;
  int COUT, CIN, KP, perm;
  switch (m) {
    case 0: W = W0; O = O0; COUT = 128; CIN = 131; KP = 160; perm = 1; break;
    case 1: W = W1; O = O1; COUT = 64; CIN = 128; KP = 128; perm = 0; break;
    case 2: W = W2; O = O2; COUT = 64; CIN = 64; KP = 64; perm = 0; break;
    case 3: W = W3; O = O3; COUT = 128; CIN = 131; KP = 160; perm = 1; break;
    default: W = W4; O = O4; COUT = 64; CIN = 128; KP = 128; perm = 0; break;
  }
  int t = blockIdx.x * 256 + threadIdx.x;
  if (t >= COUT * KP) return;
  int o = t / KP, k = t - o * KP;
  float v = 0.f;
  if (perm) {
    int c = (k < 128) ? (k + 3) : (k < 131) ? (k - 128) : -1;
    if (c >= 0) v = W[o * CIN + c];
  } else if (k < CIN) {
    v = W[o * CIN + k];
  }
  O[t] = f2bf(v);
}

// ---------------- fused gather/BN-relu + bf16-MFMA GEMM layer ------------------
template <int CIN, int COUT, int KP, int MODE, int KNN>
__global__ __launch_bounds__(256) void k_layer_mfma(
    const unsigned short* __restrict__ Wb,  // [COUT][KP] bf16
    const float* __restrict__ posP, const float* __restrict__ posQ,
    const float* __restrict__ featN, const float* __restrict__ feat1,
    const int* __restrict__ idx,
    const unsigned short* __restrict__ yprev,  // [rows][CIN] bf16 (PLAIN mode)
    const float* __restrict__ statPrev, const float* __restrict__ gPrev,
    const float* __restrict__ bPrev, float prevInvM,
    unsigned short* __restrict__ yout,  // [rows][COUT] bf16
    float* __restrict__ statOut) {
  constexpr int SP = KP + 8;
  constexpr int CST = COUT + 8;
  constexpr int CT = COUT / 64;
  __shared__ unsigned short Xs[64 * SP];
  __shared__ float scl[CIN];
  __shared__ float shf[CIN];

  int tid = threadIdx.x;
  int row0 = blockIdx.x * 64;

  if (MODE == MODE_PLAIN) {
    for (int c = tid; c < CIN; c += 256) {
      float s = 0.f, s2 = 0.f;
#pragma unroll
      for (int u = 0; u < 8; ++u) {
        s += statPrev[c * 8 + u];
        s2 += statPrev[CIN * 8 + c * 8 + u];
      }
      float m = s * prevInvM;
      float v = s2 * prevInvM - m * m;
      float sc = gPrev[c] * rsqrtf(v + EPS_);
      scl[c] = sc;
      shf[c] = bPrev[c] - m * sc;
    }
    __syncthreads();
    constexpr int S4 = KP / 4;
    for (int e = tid; e < 64 * S4; e += 256) {
      int r = e / S4, s = e - r * S4;
      int row = row0 + r;
      ushort4 u = *(const ushort4*)&yprev[(size_t)row * CIN + s * 4];
      ushort4 o;
      o.x = f2bf(fmaxf(fmaf(bf2f(u.x), scl[s * 4 + 0], shf[s * 4 + 0]), 0.f));
      o.y = f2bf(fmaxf(fmaf(bf2f(u.y), scl[s * 4 + 1], shf[s * 4 + 1]), 0.f));
      o.z = f2bf(fmaxf(fmaf(bf2f(u.z), scl[s * 4 + 2], shf[s * 4 + 2]), 0.f));
      o.w = f2bf(fmaxf(fmaf(bf2f(u.w), scl[s * 4 + 3], shf[s * 4 + 3]), 0.f));
      *(ushort4*)&Xs[r * SP + s * 4] = o;
    }
  } else {
    constexpr int S4 = KP / 4;
    for (int e = tid; e < 64 * S4; e += 256) {
      int r = e / S4, s = e - r * S4;
      int row = row0 + r;
      int b = row / (N_ * KNN);
      int rem = row - b * (N_ * KNN);
      int n = rem / KNN;
      float4 v = make_float4(0.f, 0.f, 0.f, 0.f);
      if (s < 16) {
        int j = idx[row];
        v = *(const float4*)&featN[((size_t)(b * N_ + j)) * C_ + s * 4];
      } else if (s < 32) {
        v = *(const float4*)&feat1[((size_t)(b * N_ + n)) * C_ + (s - 16) * 4];
      } else if (s == 32) {
        int j = idx[row];
        const float* pp = &posP[(size_t)(b * N_ + j) * 3];
        const float* pq = &posQ[(size_t)(b * N_ + n) * 3];
        v = make_float4(pp[0] - pq[0], pp[1] - pq[1], pp[2] - pq[2], 0.f);
      }
      ushort4 o;
      o.x = f2bf(v.x); o.y = f2bf(v.y); o.z = f2bf(v.z); o.w = f2bf(v.w);
      *(ushort4*)&Xs[r * SP + s * 4] = o;
    }
  }
  __syncthreads();

  int l = tid & 63, wv = tid >> 6;
  int lm = l & 15, quad = l >> 4;
  int n0 = wv * (COUT / 4);

  f32x4 acc[4][CT];
#pragma unroll
  for (int rt = 0; rt < 4; ++rt)
#pragma unroll
    for (int ct = 0; ct < CT; ++ct) acc[rt][ct] = (f32x4)(0.f);

#pragma unroll
  for (int k0 = 0; k0 < KP; k0 += 32) {
    bf16x8 a[4], b[CT];
#pragma unroll
    for (int rt = 0; rt < 4; ++rt)
      a[rt] = *(const bf16x8*)&Xs[(rt * 16 + lm) * SP + k0 + quad * 8];
#pragma unroll
    for (int ct = 0; ct < CT; ++ct)
      b[ct] = *(const bf16x8*)&Wb[(size_t)(n0 + ct * 16 + lm) * KP + k0 + quad * 8];
#pragma unroll
    for (int rt = 0; rt < 4; ++rt)
#pragma unroll
      for (int ct = 0; ct < CT; ++ct)
        acc[rt][ct] =
            __builtin_amdgcn_mfma_f32_16x16x32_bf16(a[rt], b[ct], acc[rt][ct], 0, 0, 0);
  }

  int slot = blockIdx.x & 7;
#pragma unroll
  for (int ct = 0; ct < CT; ++ct) {
    float s1 = 0.f, s2 = 0.f;
#pragma unroll
    for (int rt = 0; rt < 4; ++rt)
#pragma unroll
      for (int r = 0; r < 4; ++r) {
        float v = acc[rt][ct][r];
        s1 += v;
        s2 += v * v;
      }
    s1 += __shfl_xor(s1, 16);
    s1 += __shfl_xor(s1, 32);
    s2 += __shfl_xor(s2, 16);
    s2 += __shfl_xor(s2, 32);
    if (quad == 0) {
      int col = n0 + ct * 16 + lm;
      atomicAdd(&statOut[col * 8 + slot], s1);
      atomicAdd(&statOut[COUT * 8 + col * 8 + slot], s2);
    }
  }

  __syncthreads();
  unsigned short* Ys = Xs;
#pragma unroll
  for (int rt = 0; rt < 4; ++rt)
#pragma unroll
    for (int ct = 0; ct < CT; ++ct)
#pragma unroll
      for (int r = 0; r < 4; ++r)
        Ys[(rt * 16 + quad * 4 + r) * CST + n0 + ct * 16 + lm] = f2bf(acc[rt][ct][r]);
  __syncthreads();
  constexpr int S8 = COUT / 8;
  for (int e = tid; e < 64 * S8; e += 256) {
    int r = e / S8, c0 = (e - r * S8) * 8;
    uint4 v = *(const uint4*)&Ys[r * CST + c0];
    *(uint4*)&yout[((size_t)(row0 + r)) * COUT + c0] = v;
  }
}

// ---------------- fe = sum_k relu(bn(y3)), fp32 out ----------------------------
__global__ __launch_bounds__(256) void k_fe(const unsigned short* __restrict__ y3,
                                            const float* __restrict__ stat,
                                            const float* __restrict__ g,
                                            const float* __restrict__ bb,
                                            float* __restrict__ fe) {
  __shared__ float scl[C_], shf[C_];
  if (threadIdx.x < C_) {
    int c = threadIdx.x;
    float s = 0.f, s2 = 0.f;
#pragma unroll
    for (int u = 0; u < 8; ++u) {
      s += stat[c * 8 + u];
      s2 += stat[C_ * 8 + c * 8 + u];
    }
    const float invM = 1.f / (float)(BN_ * K2_);
    float m = s * invM;
    float v = s2 * invM - m * m;
    float sc = g[c] * rsqrtf(v + EPS_);
    scl[c] = sc;
    shf[c] = bb[c] - m * sc;
  }
  __syncthreads();
  int t = blockIdx.x * 256 + threadIdx.x;
  int bn = t >> 6, c = t & 63;
  float s = 0.f;
#pragma unroll
  for (int k = 0; k < K2_; ++k)
    s += fmaxf(fmaf(bf2f(y3[(size_t)(bn * K2_ + k) * C_ + c]), scl[c], shf[c]), 0.f);
  fe[t] = s;
}

// ---------------- pooled[b][c] = sum_{n,k} relu(bn(y5)) ------------------------
__global__ __launch_bounds__(256) void k_pooled(const unsigned short* __restrict__ y5,
                                                const float* __restrict__ stat,
                                                const float* __restrict__ g,
                                                const float* __restrict__ bb,
                                                float* __restrict__ pooled) {
  __shared__ float scl[C_], shf[C_];
  __shared__ float red[4][C_];
  if (threadIdx.x < C_) {
    int c = threadIdx.x;
    float s = 0.f, s2 = 0.f;
#pragma unroll
    for (int u = 0; u < 8; ++u) {
      s += stat[c * 8 + u];
      s2 += stat[C_ * 8 + c * 8 + u];
    }
    const float invM = 1.f / (float)(BN_ * K1_);
    float m = s * invM;
    float v = s2 * invM - m * m;
    float sc = g[c] * rsqrtf(v + EPS_);
    scl[c] = sc;
    shf[c] = bb[c] - m * sc;
  }
  __syncthreads();
  int c = threadIdx.x & 63;
  int rs = threadIdx.x >> 6;
  int row0 = blockIdx.x * 64;
  int b = row0 / (N_ * K1_);
  float s = 0.f;
  for (int i = 0; i < 16; ++i) {
    int row = row0 + rs * 16 + i;
    s += fmaxf(fmaf(bf2f(y5[(size_t)row * C_ + c]), scl[c], shf[c]), 0.f);
  }
  red[rs][c] = s;
  __syncthreads();
  if (threadIdx.x < C_) {
    float t2 = red[0][c] + red[1][c] + red[2][c] + red[3][c];
    atomicAdd(&pooled[(b * C_ + c) * 8 + (blockIdx.x & 7)], t2);
  }
}

// ---------------- head ---------------------------------------------------------
__global__ void k_final(const float* __restrict__ pooled, const float* __restrict__ wq,
                        const float* __restrict__ bq, const float* __restrict__ wt,
                        const float* __restrict__ bt, const float* __restrict__ qc,
                        const float* __restrict__ tc, float* __restrict__ out) {
  int b = threadIdx.x;
  if (b >= B_) return;
  float P[C_];
#pragma unroll
  for (int c = 0; c < C_; ++c) {
    float s = 0.f;
#pragma unroll
    for (int u = 0; u < 8; ++u) s += pooled[(b * C_ + c) * 8 + u];
    P[c] = s;
  }
  float qd[4];
#pragma unroll
  for (int i = 0; i < 4; ++i) {
    float s = bq[i];
#pragma unroll
    for (int c = 0; c < C_; ++c) s = fmaf(P[c], wq[i * C_ + c], s);
    qd[i] = s;
  }
  float td[3];
#pragma unroll
  for (int i = 0; i < 3; ++i) {
    float s = bt[i];
#pragma unroll
    for (int c = 0; c < C_; ++c) s = fmaf(P[c], wt[i * C_ + c], s);
    td[i] = s;
  }
  float nq = sqrtf(qd[0] * qd[0] + qd[1] * qd[1] + qd[2] * qd[2] + qd[3] * qd[3]) + 1e-10f;
#pragma unroll
  for (int i = 0; i < 4; ++i) qd[i] /= nq;
  float cw = qc[b * 4 + 0], cx = qc[b * 4 + 1], cyy = qc[b * 4 + 2], cz = qc[b * 4 + 3];
  float qnw = qd[0] * cw - qd[1] * cx - qd[2] * cyy - qd[3] * cz;
  float qnx = qd[0] * cx + qd[1] * cw + qd[2] * cz - qd[3] * cyy;
  float qny = qd[0] * cyy - qd[1] * cz + qd[2] * cw + qd[3] * cx;
  float qnz = qd[0] * cz + qd[1] * cyy - qd[2] * cx + qd[3] * cw;
  float nn = sqrtf(qnw * qnw + qnx * qnx + qny * qny + qnz * qnz) + 1e-10f;
  float vx = tc[b * 3 + 0], vy = tc[b * 3 + 1], vz = tc[b * 3 + 2];
  float aw = -(qd[1] * vx + qd[2] * vy + qd[3] * vz);
  float ax = qd[0] * vx + qd[2] * vz - qd[3] * vy;
  float ay = qd[0] * vy - qd[1] * vz + qd[3] * vx;
  float az = qd[0] * vz + qd[1] * vy - qd[2] * vx;
  float n2 = qd[0] * qd[0] + qd[1] * qd[1] + qd[2] * qd[2] + qd[3] * qd[3] + 1e-10f;
  float bw = qd[0] / n2, bx = -qd[1] / n2, by = -qd[2] / n2, bz = -qd[3] / n2;
  float rx = aw * bx + ax * bw + ay * bz - az * by;
  float ry = aw * by - ax * bz + ay * bw + az * bx;
  float rz = aw * bz + ax * by - ay * bx + az * bw;
  out[b * 7 + 0] = qnw / nn;
  out[b * 7 + 1] = qnx / nn;
  out[b * 7 + 2] = qny / nn;
  out[b * 7 + 3] = qnz / nn;
  out[b * 7 + 4] = rx + td[0];
  out[b * 7 + 5] = ry + td[1];
  out[b * 7 + 6] = rz + td[2];
}

extern "C" void kernel_launch(void* const* d_in, const int* in_sizes, int n_in,
                              void* d_out, int out_size, void* d_ws, size_t ws_size,
                              hipStream_t stream) {
  const float* pos1 = (const float*)d_in[0];
  const float* pos2 = (const float*)d_in[1];
  const float* feat1 = (const float*)d_in[2];
  const float* feat2 = (const float*)d_in[3];
  const float* qc = (const float*)d_in[4];
  const float* tc = (const float*)d_in[5];
  const float* w1_0 = (const float*)d_in[6];
  const float* g1_0 = (const float*)d_in[7];
  const float* b1_0 = (const float*)d_in[8];
  const float* w1_1 = (const float*)d_in[9];
  const float* g1_1 = (const float*)d_in[10];
  const float* b1_1 = (const float*)d_in[11];
  const float* w1_2 = (const float*)d_in[12];
  const float* g1_2 = (const float*)d_in[13];
  const float* b1_2 = (const float*)d_in[14];
  const float* w2_0 = (const float*)d_in[15];
  const float* g2_0 = (const float*)d_in[16];
  const float* b2_0 = (const float*)d_in[17];
  const float* w2_1 = (const float*)d_in[18];
  const float* g2_1 = (const float*)d_in[19];
  const float* b2_1 = (const float*)d_in[20];
  const float* wq = (const float*)d_in[21];
  const float* bq = (const float*)d_in[22];
  const float* wt = (const float*)d_in[23];
  const float* bt = (const float*)d_in[24];

  float* ws = (float*)d_ws;
  const size_t off_posw = 0;                  // 49152
  const size_t off_fe = 49152;                // 1048576 (fp32)
  const size_t off_stat = 1097728;            // 8192
  const size_t off_pool = 1105920;            // 2048
  const size_t off_idx2 = 1107968;            // 98304 (int)
  const size_t off_idx1 = 1206272;            // 65536 (int)
  const size_t off_wb = 1271808;              // 30720 floats = 61440 bf16
  const size_t off_pts2 = 1302528;            // 65536 (float4 x 16384)
  const size_t off_ptsw = 1368064;            // 65536
  const size_t off_yA = 1433600;              // 6291456 floats = 12582912 bf16
  const size_t off_yB = 7725056;              // 3145728 floats = 6291456 bf16

  float* posw = ws + off_posw;
  float* fe = ws + off_fe;
  float* stat0 = ws + off_stat;  // 128*16
  float* stat1 = stat0 + 2048;   // 64*16
  float* stat2 = stat1 + 1024;   // 64*16
  float* stat3 = stat2 + 1024;   // 128*16
  float* stat4 = stat3 + 2048;   // 64*16
  float* pooled = ws + off_pool;
  int* idx2 = (int*)(ws + off_idx2);
  int* idx1 = (int*)(ws + off_idx1);
  unsigned short* wb0 = (unsigned short*)(ws + off_wb);  // 128x160
  unsigned short* wb1 = wb0 + 20480;                     // 64x128
  unsigned short* wb2 = wb1 + 8192;                      // 64x64
  unsigned short* wb3 = wb2 + 4096;                      // 128x160
  unsigned short* wb4 = wb3 + 20480;                     // 64x128
  float4* pts4p = (float4*)(ws + off_pts2);
  float4* pts4w = (float4*)(ws + off_ptsw);
  unsigned short* yA = (unsigned short*)(ws + off_yA);
  unsigned short* yB = (unsigned short*)(ws + off_yB);
  // KNN scratch overlaps yA (used strictly before the layer kernels)
  // needs 2*BN*NCH*6 = 1,572,864 floats for D + same for I = 3.1M floats < 6.29M
  float* knnD = (float*)yA;
  int* knnI = (int*)(knnD + 2 * BN_ * NCH_ * 6);

  hipMemsetAsync(ws + off_stat, 0, (8192 + 2048) * sizeof(float), stream);

  k_wconv_all<<<dim3(80, 5), 256, 0, stream>>>(w1_0, w1_1, w1_2, w2_0, w2_1, wb0, wb1,
                                               wb2, wb3, wb4);
  k_pose<<<dim3(BN_ / 256), 256, 0, stream>>>(pos1, pos2, qc, tc, posw, pts4w, pts4p);

  // fused dual KNN: grid (16 query-blocks, 8 chunks, 4 batches x 2 KNNs)
  k_knn2<<<dim3(N_ / 256, NCH_, 2 * B_), 256, 0, stream>>>(pts4w, pts4p, knnD, knnI);
  k_knn2_merge<<<dim3(2 * BN_ / 256), 256, 0, stream>>>(knnD, knnI, idx2, idx1);

  // MLP1 L0: gather(pos2,feat2)+feat1 -> 128ch, y into yA
  k_layer_mfma<131, 128, 160, MODE_GATHER, K2_><<<dim3(98304 / 64), 256, 0, stream>>>(
      wb0, pos2, posw, feat2, feat1, idx2, nullptr, nullptr, nullptr, nullptr, 0.f, yA,
      stat0);
  // MLP1 L1: 128->64, yA -> yB
  k_layer_mfma<128, 64, 128, MODE_PLAIN, 1><<<dim3(98304 / 64), 256, 0, stream>>>(
      wb1, nullptr, nullptr, nullptr, nullptr, nullptr, yA, stat0, g1_0, b1_0,
      1.f / 98304.f, yB, stat1);
  // MLP1 L2: 64->64, yB -> yA
  k_layer_mfma<64, 64, 64, MODE_PLAIN, 1><<<dim3(98304 / 64), 256, 0, stream>>>(
      wb2, nullptr, nullptr, nullptr, nullptr, nullptr, yB, stat1, g1_1, b1_1,
      1.f / 98304.f, yA, stat2);
  // fe = sum_k relu(bn(yA))
  k_fe<<<dim3(BN_ * C_ / 256), 256, 0, stream>>>(yA, stat2, g1_2, b1_2, fe);
  // MLP2 L0: gather(posw, fe)+feat1 -> 128ch, into yA
  k_layer_mfma<131, 128, 160, MODE_GATHER, K1_><<<dim3(65536 / 64), 256, 0, stream>>>(
      wb3, posw, posw, fe, feat1, idx1, nullptr, nullptr, nullptr, nullptr, 0.f, yA,
      stat3);
  // MLP2 L1: 128->64, yA -> yB
  k_layer_mfma<128, 64, 128, MODE_PLAIN, 1><<<dim3(65536 / 64), 256, 0, stream>>>(
      wb4, nullptr, nullptr, nullptr, nullptr, nullptr, yA, stat3, g2_0, b2_0,
      1.f / 65536.f, yB, stat4);
  // pooled
  k_pooled<<<dim3(65536 / 64), 256, 0, stream>>>(yB, stat4, g2_1, b2_1, pooled);
  // head
  k_final<<<dim3(1), 64, 0, stream>>>(pooled, wq, bq, wt, bt, qc, tc, (float*)d_out);
}

// Round 5
// 453.763 us; speedup vs baseline: 2.2286x; 1.0305x over previous
//
#include <hip/hip_runtime.h>
#include <math.h>

#define B_ 4
#define N_ 4096
#define C_ 64
#define K1_ 4
#define K2_ 6
#define EPS_ 1e-5f
#define BN_ (B_ * N_)
#define NCH_ 8
#define CHP_ 512
#define STKD_ 16

#define MODE_GATHER 0
#define MODE_PLAIN 2

typedef __attribute__((ext_vector_type(8))) short bf16x8;
typedef __attribute__((ext_vector_type(4))) float f32x4;
typedef __attribute__((ext_vector_type(2))) float f32x2;

__device__ __forceinline__ unsigned short f2bf(float f) {
  unsigned int u = __float_as_uint(f);
  unsigned int r = (u + 0x7fffu + ((u >> 16) & 1u)) >> 16;
  return (unsigned short)r;
}
__device__ __forceinline__ float bf2f(unsigned short u) {
  return __uint_as_float(((unsigned int)u) << 16);
}

// ---------------- pose + point-table build -------------------------------------
// pos1_w = qrot(q_coarse,pos1)+t. Emits:
//  pts4w: (x,y,z,|p|^2) per warped query point
//  pairW/pairP: pair-interleaved target tables [x0 x1 y0 y1][z0 z1 w0 w1]
//  (wave-uniform loads + packed-fp32 distance math in k_knn2)
__global__ __launch_bounds__(256) void k_pose(const float* __restrict__ pos1,
                                              const float* __restrict__ pos2,
                                              const float* __restrict__ qc,
                                              const float* __restrict__ tc,
                                              float* __restrict__ posw,
                                              float4* __restrict__ pts4w,
                                              float4* __restrict__ pairW,
                                              float4* __restrict__ pairP) {
  int t = blockIdx.x * 256 + threadIdx.x;
  if (t >= BN_) return;
  int b = t / N_;
  float qw = qc[b * 4 + 0], qx = qc[b * 4 + 1], qy = qc[b * 4 + 2], qz = qc[b * 4 + 3];
  float vx = pos1[t * 3 + 0], vy = pos1[t * 3 + 1], vz = pos1[t * 3 + 2];
  float aw = -(qx * vx + qy * vy + qz * vz);
  float ax = qw * vx + qy * vz - qz * vy;
  float ay = qw * vy - qx * vz + qz * vx;
  float az = qw * vz + qx * vy - qy * vx;
  float n2 = qw * qw + qx * qx + qy * qy + qz * qz + 1e-10f;
  float bw = qw / n2, bx = -qx / n2, by = -qy / n2, bz = -qz / n2;
  float rx = aw * bx + ax * bw + ay * bz - az * by;
  float ry = aw * by - ax * bz + ay * bw + az * bx;
  float rz = aw * bz + ax * by - ay * bx + az * bw;
  rx += tc[b * 3 + 0];
  ry += tc[b * 3 + 1];
  rz += tc[b * 3 + 2];
  posw[t * 3 + 0] = rx;
  posw[t * 3 + 1] = ry;
  posw[t * 3 + 2] = rz;
  float rw2 = rx * rx + ry * ry + rz * rz;
  pts4w[t] = make_float4(rx, ry, rz, rw2);
  int p = t >> 1, h = t & 1;
  float* bwp = (float*)&pairW[(size_t)2 * p];
  bwp[0 + h] = rx; bwp[2 + h] = ry; bwp[4 + h] = rz; bwp[6 + h] = rw2;
  float px = pos2[t * 3 + 0], py = pos2[t * 3 + 1], pz = pos2[t * 3 + 2];
  float pw2 = px * px + py * py + pz * pz;
  float* bpp = (float*)&pairP[(size_t)2 * p];
  bpp[0 + h] = px; bpp[2 + h] = py; bpp[4 + h] = pz; bpp[6 + h] = pw2;
}

// ---------------- stable top-6 insert on packed int keys -----------------------
// key = (float_bits(d) & 0xFFFFF000) | j ; signed-int order == (d, j) lexicographic
// for d>=0; negative d (self-match only) sorts first. Keys are unique (j unique).
__device__ __forceinline__ void ins6i(int (&kd)[6], int k) {
  if (k < kd[5]) {
    int pos = 0;
#pragma unroll
    for (int t = 0; t < 5; ++t) pos += (kd[t] <= k) ? 1 : 0;
#pragma unroll
    for (int u = 5; u > 0; --u) kd[u] = (u > pos) ? kd[u - 1] : kd[u];
#pragma unroll
    for (int u = 0; u < 6; ++u)
      if (u == pos) kd[u] = k;
  }
}

// ---------------- fused dual-KNN, packed keys + LDS candidate stacks -----------
// blockIdx.z: b = z&3, which = z>>2 (0: vs pos2 for idx2, 1: vs posw for idx1)
__global__ __launch_bounds__(256) void k_knn2(const float4* __restrict__ pts4w,
                                              const float4* __restrict__ pairW,
                                              const float4* __restrict__ pairP,
                                              int* __restrict__ outK) {
  __shared__ int st[STKD_][256];
  int tid = threadIdx.x;
  int b = blockIdx.z & 3;
  int which = blockIdx.z >> 2;
  const f32x4* __restrict__ PT =
      (const f32x4*)((which ? pairW : pairP) + (size_t)b * N_ + blockIdx.y * CHP_);
  int base = blockIdx.y * CHP_;
  int n = blockIdx.x * 256 + tid;
  float4 qv = pts4w[(size_t)b * N_ + n];
  f32x2 qq2 = (f32x2)(qv.w);
  f32x2 m2x = (f32x2)(-2.f * qv.x);
  f32x2 m2y = (f32x2)(-2.f * qv.y);
  f32x2 m2z = (f32x2)(-2.f * qv.z);
  int kd[6];
#pragma unroll
  for (int t = 0; t < 6; ++t) kd[t] = 0x7fffffff;
  int kbd5 = 0x7fffffff;
  int ptr = 0;
  for (int jj = 0; jj < CHP_; jj += 4) {
    f32x4 e0 = PT[jj + 0];  // x0 x1 y0 y1
    f32x4 e1 = PT[jj + 1];  // z0 z1 w0 w1
    f32x4 e2 = PT[jj + 2];
    f32x4 e3 = PT[jj + 3];
    f32x2 d01 = __builtin_elementwise_fma(
        m2x, e0.xy,
        __builtin_elementwise_fma(m2y, e0.zw,
                                  __builtin_elementwise_fma(m2z, e1.xy, e1.zw + qq2)));
    f32x2 d23 = __builtin_elementwise_fma(
        m2x, e2.xy,
        __builtin_elementwise_fma(m2y, e2.zw,
                                  __builtin_elementwise_fma(m2z, e3.xy, e3.zw + qq2)));
    int j0 = base + jj;
    int k0 = (int)((__float_as_uint(d01.x) & 0xFFFFF000u) | (unsigned)(j0 + 0));
    int k1 = (int)((__float_as_uint(d01.y) & 0xFFFFF000u) | (unsigned)(j0 + 1));
    int k2 = (int)((__float_as_uint(d23.x) & 0xFFFFF000u) | (unsigned)(j0 + 2));
    int k3 = (int)((__float_as_uint(d23.y) & 0xFFFFF000u) | (unsigned)(j0 + 3));
    st[ptr][tid] = k0;
    ptr += (k0 < kbd5) ? 1 : 0;
    st[ptr][tid] = k1;
    ptr += (k1 < kbd5) ? 1 : 0;
    st[ptr][tid] = k2;
    ptr += (k2 < kbd5) ? 1 : 0;
    st[ptr][tid] = k3;
    ptr += (k3 < kbd5) ? 1 : 0;
    if (__ballot(ptr >= STKD_ - 4)) {
      for (int i = 0; i < ptr; ++i) ins6i(kd, st[i][tid]);
      ptr = 0;
      kbd5 = kd[5];
    }
  }
  for (int i = 0; i < ptr; ++i) ins6i(kd, st[i][tid]);
  size_t ob =
      ((size_t)which * BN_ * NCH_ + (size_t)(b * N_ + n) * NCH_ + blockIdx.y) * 6;
#pragma unroll
  for (int t = 0; t < 6; ++t) outK[ob + t] = kd[t];
}

__global__ __launch_bounds__(64) void k_knn2_merge(const int* __restrict__ inK,
                                                   int* __restrict__ idx2,
                                                   int* __restrict__ idx1) {
  int t = blockIdx.x * 64 + threadIdx.x;
  if (t >= 2 * BN_) return;
  int which = (t >= BN_) ? 1 : 0;
  int qi = t - which * BN_;
  int kd[6];
#pragma unroll
  for (int u = 0; u < 6; ++u) kd[u] = 0x7fffffff;
  size_t ib = ((size_t)which * BN_ + qi) * NCH_ * 6;
  for (int c = 0; c < NCH_ * 6; ++c) ins6i(kd, inK[ib + c]);
  if (which) {
#pragma unroll
    for (int u = 0; u < K1_; ++u) idx1[(size_t)qi * K1_ + u] = kd[u] & 0xFFF;
  } else {
#pragma unroll
    for (int u = 0; u < K2_; ++u) idx2[(size_t)qi * K2_ + u] = kd[u] & 0xFFF;
  }
}

// ---------------- weight pre-conversion to bf16 (padded, permuted) -------------
__global__ __launch_bounds__(256) void k_wconv_all(
    const float* __restrict__ W0, const float* __restrict__ W1,
    const float* __restrict__ W2, const float* __restrict__ W3,
    const float* __restrict__ W4, unsigned short* __restrict__ O0,
    unsigned short* __restrict__ O1, unsigned short* __restrict__ O2,
    unsigned short* __restrict__ O3, unsigned short* __restrict__ O4) {
  int m = blockIdx.y;
  const float* W;
  unsigned short* O;
  int COUT, CIN, KP, perm;
  switch (m) {
    case 0: W = W0; O = O0; COUT = 128; CIN = 131; KP = 160; perm = 1; break;
    case 1: W = W1; O = O1; COUT = 64; CIN = 128; KP = 128; perm = 0; break;
    case 2: W = W2; O = O2; COUT = 64; CIN = 64; KP = 64; perm = 0; break;
    case 3: W = W3; O = O3; COUT = 128; CIN = 131; KP = 160; perm = 1; break;
    default: W = W4; O = O4; COUT = 64; CIN = 128; KP = 128; perm = 0; break;
  }
  int t = blockIdx.x * 256 + threadIdx.x;
  if (t >= COUT * KP) return;
  int o = t / KP, k = t - o * KP;
  float v = 0.f;
  if (perm) {
    int c = (k < 128) ? (k + 3) : (k < 131) ? (k - 128) : -1;
    if (c >= 0) v = W[o * CIN + c];
  } else if (k < CIN) {
    v = W[o * CIN + k];
  }
  O[t] = f2bf(v);
}

// ---------------- fused gather/BN-relu + bf16-MFMA GEMM layer ------------------
template <int CIN, int COUT, int KP, int MODE, int KNN>
__global__ __launch_bounds__(256) void k_layer_mfma(
    const unsigned short* __restrict__ Wb,  // [COUT][KP] bf16
    const float* __restrict__ posP, const float* __restrict__ posQ,
    const float* __restrict__ featN, const float* __restrict__ feat1,
    const int* __restrict__ idx,
    const unsigned short* __restrict__ yprev,  // [rows][CIN] bf16 (PLAIN mode)
    const float* __restrict__ statPrev, const float* __restrict__ gPrev,
    const float* __restrict__ bPrev, float prevInvM,
    unsigned short* __restrict__ yout,  // [rows][COUT] bf16
    float* __restrict__ statOut) {
  constexpr int SP = KP + 8;
  constexpr int CST = COUT + 8;
  constexpr int CT = COUT / 64;
  __shared__ unsigned short Xs[64 * SP];
  __shared__ float scl[CIN];
  __shared__ float shf[CIN];

  int tid = threadIdx.x;
  int row0 = blockIdx.x * 64;

  if (MODE == MODE_PLAIN) {
    for (int c = tid; c < CIN; c += 256) {
      float s = 0.f, s2 = 0.f;
#pragma unroll
      for (int u = 0; u < 8; ++u) {
        s += statPrev[c * 8 + u];
        s2 += statPrev[CIN * 8 + c * 8 + u];
      }
      float m = s * prevInvM;
      float v = s2 * prevInvM - m * m;
      float sc = gPrev[c] * rsqrtf(v + EPS_);
      scl[c] = sc;
      shf[c] = bPrev[c] - m * sc;
    }
    __syncthreads();
    constexpr int S4 = KP / 4;
    for (int e = tid; e < 64 * S4; e += 256) {
      int r = e / S4, s = e - r * S4;
      int row = row0 + r;
      ushort4 u = *(const ushort4*)&yprev[(size_t)row * CIN + s * 4];
      ushort4 o;
      o.x = f2bf(fmaxf(fmaf(bf2f(u.x), scl[s * 4 + 0], shf[s * 4 + 0]), 0.f));
      o.y = f2bf(fmaxf(fmaf(bf2f(u.y), scl[s * 4 + 1], shf[s * 4 + 1]), 0.f));
      o.z = f2bf(fmaxf(fmaf(bf2f(u.z), scl[s * 4 + 2], shf[s * 4 + 2]), 0.f));
      o.w = f2bf(fmaxf(fmaf(bf2f(u.w), scl[s * 4 + 3], shf[s * 4 + 3]), 0.f));
      *(ushort4*)&Xs[r * SP + s * 4] = o;
    }
  } else {
    constexpr int S4 = KP / 4;
    for (int e = tid; e < 64 * S4; e += 256) {
      int r = e / S4, s = e - r * S4;
      int row = row0 + r;
      int b = row / (N_ * KNN);
      int rem = row - b * (N_ * KNN);
      int n = rem / KNN;
      float4 v = make_float4(0.f, 0.f, 0.f, 0.f);
      if (s < 16) {
        int j = idx[row];
        v = *(const float4*)&featN[((size_t)(b * N_ + j)) * C_ + s * 4];
      } else if (s < 32) {
        v = *(const float4*)&feat1[((size_t)(b * N_ + n)) * C_ + (s - 16) * 4];
      } else if (s == 32) {
        int j = idx[row];
        const float* pp = &posP[(size_t)(b * N_ + j) * 3];
        const float* pq = &posQ[(size_t)(b * N_ + n) * 3];
        v = make_float4(pp[0] - pq[0], pp[1] - pq[1], pp[2] - pq[2], 0.f);
      }
      ushort4 o;
      o.x = f2bf(v.x); o.y = f2bf(v.y); o.z = f2bf(v.z); o.w = f2bf(v.w);
      *(ushort4*)&Xs[r * SP + s * 4] = o;
    }
  }
  __syncthreads();

  int l = tid & 63, wv = tid >> 6;
  int lm = l & 15, quad = l >> 4;
  int n0 = wv * (COUT / 4);

  f32x4 acc[4][CT];
#pragma unroll
  for (int rt = 0; rt < 4; ++rt)
#pragma unroll
    for (int ct = 0; ct < CT; ++ct) acc[rt][ct] = (f32x4)(0.f);

#pragma unroll
  for (int k0 = 0; k0 < KP; k0 += 32) {
    bf16x8 a[4], b[CT];
#pragma unroll
    for (int rt = 0; rt < 4; ++rt)
      a[rt] = *(const bf16x8*)&Xs[(rt * 16 + lm) * SP + k0 + quad * 8];
#pragma unroll
    for (int ct = 0; ct < CT; ++ct)
      b[ct] = *(const bf16x8*)&Wb[(size_t)(n0 + ct * 16 + lm) * KP + k0 + quad * 8];
#pragma unroll
    for (int rt = 0; rt < 4; ++rt)
#pragma unroll
      for (int ct = 0; ct < CT; ++ct)
        acc[rt][ct] =
            __builtin_amdgcn_mfma_f32_16x16x32_bf16(a[rt], b[ct], acc[rt][ct], 0, 0, 0);
  }

  int slot = blockIdx.x & 7;
#pragma unroll
  for (int ct = 0; ct < CT; ++ct) {
    float s1 = 0.f, s2 = 0.f;
#pragma unroll
    for (int rt = 0; rt < 4; ++rt)
#pragma unroll
      for (int r = 0; r < 4; ++r) {
        float v = acc[rt][ct][r];
        s1 += v;
        s2 += v * v;
      }
    s1 += __shfl_xor(s1, 16);
    s1 += __shfl_xor(s1, 32);
    s2 += __shfl_xor(s2, 16);
    s2 += __shfl_xor(s2, 32);
    if (quad == 0) {
      int col = n0 + ct * 16 + lm;
      atomicAdd(&statOut[col * 8 + slot], s1);
      atomicAdd(&statOut[COUT * 8 + col * 8 + slot], s2);
    }
  }

  __syncthreads();
  unsigned short* Ys = Xs;
#pragma unroll
  for (int rt = 0; rt < 4; ++rt)
#pragma unroll
    for (int ct = 0; ct < CT; ++ct)
#pragma unroll
      for (int r = 0; r < 4; ++r)
        Ys[(rt * 16 + quad * 4 + r) * CST + n0 + ct * 16 + lm] = f2bf(acc[rt][ct][r]);
  __syncthreads();
  constexpr int S8 = COUT / 8;
  for (int e = tid; e < 64 * S8; e += 256) {
    int r = e / S8, c0 = (e - r * S8) * 8;
    uint4 v = *(const uint4*)&Ys[r * CST + c0];
    *(uint4*)&yout[((size_t)(row0 + r)) * COUT + c0] = v;
  }
}

// ---------------- fe = sum_k relu(bn(y3)), fp32 out ----------------------------
__global__ __launch_bounds__(256) void k_fe(const unsigned short* __restrict__ y3,
                                            const float* __restrict__ stat,
                                            const float* __restrict__ g,
                                            const float* __restrict__ bb,
                                            float* __restrict__ fe) {
  __shared__ float scl[C_], shf[C_];
  if (threadIdx.x < C_) {
    int c = threadIdx.x;
    float s = 0.f, s2 = 0.f;
#pragma unroll
    for (int u = 0; u < 8; ++u) {
      s += stat[c * 8 + u];
      s2 += stat[C_ * 8 + c * 8 + u];
    }
    const float invM = 1.f / (float)(BN_ * K2_);
    float m = s * invM;
    float v = s2 * invM - m * m;
    float sc = g[c] * rsqrtf(v + EPS_);
    scl[c] = sc;
    shf[c] = bb[c] - m * sc;
  }
  __syncthreads();
  int t = blockIdx.x * 256 + threadIdx.x;
  int bn = t >> 6, c = t & 63;
  float s = 0.f;
#pragma unroll
  for (int k = 0; k < K2_; ++k)
    s += fmaxf(fmaf(bf2f(y3[(size_t)(bn * K2_ + k) * C_ + c]), scl[c], shf[c]), 0.f);
  fe[t] = s;
}

// ---------------- pooled[b][c] = sum_{n,k} relu(bn(y5)) ------------------------
__global__ __launch_bounds__(256) void k_pooled(const unsigned short* __restrict__ y5,
                                                const float* __restrict__ stat,
                                                const float* __restrict__ g,
                                                const float* __restrict__ bb,
                                                float* __restrict__ pooled) {
  __shared__ float scl[C_], shf[C_];
  __shared__ float red[4][C_];
  if (threadIdx.x < C_) {
    int c = threadIdx.x;
    float s = 0.f, s2 = 0.f;
#pragma unroll
    for (int u = 0; u < 8; ++u) {
      s += stat[c * 8 + u];
      s2 += stat[C_ * 8 + c * 8 + u];
    }
    const float invM = 1.f / (float)(BN_ * K1_);
    float m = s * invM;
    float v = s2 * invM - m * m;
    float sc = g[c] * rsqrtf(v + EPS_);
    scl[c] = sc;
    shf[c] = bb[c] - m * sc;
  }
  __syncthreads();
  int c = threadIdx.x & 63;
  int rs = threadIdx.x >> 6;
  int row0 = blockIdx.x * 64;
  int b = row0 / (N_ * K1_);
  float s = 0.f;
  for (int i = 0; i < 16; ++i) {
    int row = row0 + rs * 16 + i;
    s += fmaxf(fmaf(bf2f(y5[(size_t)row * C_ + c]), scl[c], shf[c]), 0.f);
  }
  red[rs][c] = s;
  __syncthreads();
  if (threadIdx.x < C_) {
    float t2 = red[0][c] + red[1][c] + red[2][c] + red[3][c];
    atomicAdd(&pooled[(b * C_ + c) * 8 + (blockIdx.x & 7)], t2);
  }
}

// ---------------- head ---------------------------------------------------------
__global__ void k_final(const float* __restrict__ pooled, const float* __restrict__ wq,
                        const float* __restrict__ bq, const float* __restrict__ wt,
                        const float* __restrict__ bt, const float* __restrict__ qc,
                        const float* __restrict__ tc, float* __restrict__ out) {
  int b = threadIdx.x;
  if (b >= B_) return;
  float P[C_];
#pragma unroll
  for (int c = 0; c < C_; ++c) {
    float s = 0.f;
#pragma unroll
    for (int u = 0; u < 8; ++u) s += pooled[(b * C_ + c) * 8 + u];
    P[c] = s;
  }
  float qd[4];
#pragma unroll
  for (int i = 0; i < 4; ++i) {
    float s = bq[i];
#pragma unroll
    for (int c = 0; c < C_; ++c) s = fmaf(P[c], wq[i * C_ + c], s);
    qd[i] = s;
  }
  float td[3];
#pragma unroll
  for (int i = 0; i < 3; ++i) {
    float s = bt[i];
#pragma unroll
    for (int c = 0; c < C_; ++c) s = fmaf(P[c], wt[i * C_ + c], s);
    td[i] = s;
  }
  float nq = sqrtf(qd[0] * qd[0] + qd[1] * qd[1] + qd[2] * qd[2] + qd[3] * qd[3]) + 1e-10f;
#pragma unroll
  for (int i = 0; i < 4; ++i) qd[i] /= nq;
  float cw = qc[b * 4 + 0], cx = qc[b * 4 + 1], cyy = qc[b * 4 + 2], cz = qc[b * 4 + 3];
  float qnw = qd[0] * cw - qd[1] * cx - qd[2] * cyy - qd[3] * cz;
  float qnx = qd[0] * cx + qd[1] * cw + qd[2] * cz - qd[3] * cyy;
  float qny = qd[0] * cyy - qd[1] * cz + qd[2] * cw + qd[3] * cx;
  float qnz = qd[0] * cz + qd[1] * cyy - qd[2] * cx + qd[3] * cw;
  float nn = sqrtf(qnw * qnw + qnx * qnx + qny * qny + qnz * qnz) + 1e-10f;
  float vx = tc[b * 3 + 0], vy = tc[b * 3 + 1], vz = tc[b * 3 + 2];
  float aw = -(qd[1] * vx + qd[2] * vy + qd[3] * vz);
  float ax = qd[0] * vx + qd[2] * vz - qd[3] * vy;
  float ay = qd[0] * vy - qd[1] * vz + qd[3] * vx;
  float az = qd[0] * vz + qd[1] * vy - qd[2] * vx;
  float n2 = qd[0] * qd[0] + qd[1] * qd[1] + qd[2] * qd[2] + qd[3] * qd[3] + 1e-10f;
  float bw = qd[0] / n2, bx = -qd[1] / n2, by = -qd[2] / n2, bz = -qd[3] / n2;
  float rx = aw * bx + ax * bw + ay * bz - az * by;
  float ry = aw * by - ax * bz + ay * bw + az * bx;
  float rz = aw * bz + ax * by - ay * bx + az * bw;
  out[b * 7 + 0] = qnw / nn;
  out[b * 7 + 1] = qnx / nn;
  out[b * 7 + 2] = qny / nn;
  out[b * 7 + 3] = qnz / nn;
  out[b * 7 + 4] = rx + td[0];
  out[b * 7 + 5] = ry + td[1];
  out[b * 7 + 6] = rz + td[2];
}

extern "C" void kernel_launch(void* const* d_in, const int* in_sizes, int n_in,
                              void* d_out, int out_size, void* d_ws, size_t ws_size,
                              hipStream_t stream) {
  const float* pos1 = (const float*)d_in[0];
  const float* pos2 = (const float*)d_in[1];
  const float* feat1 = (const float*)d_in[2];
  const float* feat2 = (const float*)d_in[3];
  const float* qc = (const float*)d_in[4];
  const float* tc = (const float*)d_in[5];
  const float* w1_0 = (const float*)d_in[6];
  const float* g1_0 = (const float*)d_in[7];
  const float* b1_0 = (const float*)d_in[8];
  const float* w1_1 = (const float*)d_in[9];
  const float* g1_1 = (const float*)d_in[10];
  const float* b1_1 = (const float*)d_in[11];
  const float* w1_2 = (const float*)d_in[12];
  const float* g1_2 = (const float*)d_in[13];
  const float* b1_2 = (const float*)d_in[14];
  const float* w2_0 = (const float*)d_in[15];
  const float* g2_0 = (const float*)d_in[16];
  const float* b2_0 = (const float*)d_in[17];
  const float* w2_1 = (const float*)d_in[18];
  const float* g2_1 = (const float*)d_in[19];
  const float* b2_1 = (const float*)d_in[20];
  const float* wq = (const float*)d_in[21];
  const float* bq = (const float*)d_in[22];
  const float* wt = (const float*)d_in[23];
  const float* bt = (const float*)d_in[24];

  float* ws = (float*)d_ws;
  const size_t off_posw = 0;                  // 49152
  const size_t off_fe = 49152;                // 1048576 (fp32)
  const size_t off_stat = 1097728;            // 8192
  const size_t off_pool = 1105920;            // 2048
  const size_t off_idx2 = 1107968;            // 98304 (int)
  const size_t off_idx1 = 1206272;            // 65536 (int)
  const size_t off_wb = 1271808;              // 30720 floats = 61440 bf16
  const size_t off_pts4w = 1302528;           // 65536 (float4 x 16384)
  const size_t off_pairW = 1368064;           // 65536
  const size_t off_pairP = 1433600;           // 65536
  const size_t off_yA = 1499136;              // 6291456 floats = 12582912 bf16
  const size_t off_yB = 7790592;              // 3145728 floats = 6291456 bf16

  float* posw = ws + off_posw;
  float* fe = ws + off_fe;
  float* stat0 = ws + off_stat;  // 128*16
  float* stat1 = stat0 + 2048;   // 64*16
  float* stat2 = stat1 + 1024;   // 64*16
  float* stat3 = stat2 + 1024;   // 128*16
  float* stat4 = stat3 + 2048;   // 64*16
  float* pooled = ws + off_pool;
  int* idx2 = (int*)(ws + off_idx2);
  int* idx1 = (int*)(ws + off_idx1);
  unsigned short* wb0 = (unsigned short*)(ws + off_wb);  // 128x160
  unsigned short* wb1 = wb0 + 20480;                     // 64x128
  unsigned short* wb2 = wb1 + 8192;                      // 64x64
  unsigned short* wb3 = wb2 + 4096;                      // 128x160
  unsigned short* wb4 = wb3 + 20480;                     // 64x128
  float4* pts4w = (float4*)(ws + off_pts4w);
  float4* pairW = (float4*)(ws + off_pairW);
  float4* pairP = (float4*)(ws + off_pairP);
  unsigned short* yA = (unsigned short*)(ws + off_yA);
  unsigned short* yB = (unsigned short*)(ws + off_yB);
  // KNN partial-key scratch overlaps yA (used strictly before the layer kernels)
  // needs 2*BN*NCH*6 = 1,572,864 ints < 6.29M floats
  int* knnK = (int*)yA;

  hipMemsetAsync(ws + off_stat, 0, (8192 + 2048) * sizeof(float), stream);

  k_wconv_all<<<dim3(80, 5), 256, 0, stream>>>(w1_0, w1_1, w1_2, w2_0, w2_1, wb0, wb1,
                                               wb2, wb3, wb4);
  k_pose<<<dim3(BN_ / 256), 256, 0, stream>>>(pos1, pos2, qc, tc, posw, pts4w, pairW,
                                              pairP);

  // fused dual KNN: grid (16 query-blocks, 8 chunks, 4 batches x 2 KNNs)
  k_knn2<<<dim3(N_ / 256, NCH_, 2 * B_), 256, 0, stream>>>(pts4w, pairW, pairP, knnK);
  k_knn2_merge<<<dim3(2 * BN_ / 64), 64, 0, stream>>>(knnK, idx2, idx1);

  // MLP1 L0: gather(pos2,feat2)+feat1 -> 128ch, y into yA
  k_layer_mfma<131, 128, 160, MODE_GATHER, K2_><<<dim3(98304 / 64), 256, 0, stream>>>(
      wb0, pos2, posw, feat2, feat1, idx2, nullptr, nullptr, nullptr, nullptr, 0.f, yA,
      stat0);
  // MLP1 L1: 128->64, yA -> yB
  k_layer_mfma<128, 64, 128, MODE_PLAIN, 1><<<dim3(98304 / 64), 256, 0, stream>>>(
      wb1, nullptr, nullptr, nullptr, nullptr, nullptr, yA, stat0, g1_0, b1_0,
      1.f / 98304.f, yB, stat1);
  // MLP1 L2: 64->64, yB -> yA
  k_layer_mfma<64, 64, 64, MODE_PLAIN, 1><<<dim3(98304 / 64), 256, 0, stream>>>(
      wb2, nullptr, nullptr, nullptr, nullptr, nullptr, yB, stat1, g1_1, b1_1,
      1.f / 98304.f, yA, stat2);
  // fe = sum_k relu(bn(yA))
  k_fe<<<dim3(BN_ * C_ / 256), 256, 0, stream>>>(yA, stat2, g1_2, b1_2, fe);
  // MLP2 L0: gather(posw, fe)+feat1 -> 128ch, into yA
  k_layer_mfma<131, 128, 160, MODE_GATHER, K1_><<<dim3(65536 / 64), 256, 0, stream>>>(
      wb3, posw, posw, fe, feat1, idx1, nullptr, nullptr, nullptr, nullptr, 0.f, yA,
      stat3);
  // MLP2 L1: 128->64, yA -> yB
  k_layer_mfma<128, 64, 128, MODE_PLAIN, 1><<<dim3(65536 / 64), 256, 0, stream>>>(
      wb4, nullptr, nullptr, nullptr, nullptr, nullptr, yA, stat3, g2_0, b2_0,
      1.f / 65536.f, yB, stat4);
  // pooled
  k_pooled<<<dim3(65536 / 64), 256, 0, stream>>>(yB, stat4, g2_1, b2_1, pooled);
  // head
  k_final<<<dim3(1), 64, 0, stream>>>(pooled, wq, bq, wt, bt, qc, tc, (float*)d_out);
}